// Round 5
// baseline (514.668 us; speedup 1.0000x reference)
//
#include <hip/hip_runtime.h>

#define NTOK 8192
#define CDIM 1024
#define HDIM 128

typedef __attribute__((ext_vector_type(8))) short short8;
typedef __attribute__((ext_vector_type(4))) float floatx4;
typedef __attribute__((ext_vector_type(4))) unsigned short ushort4v;

__device__ inline unsigned short f2bf(float f) {
    union { float f; unsigned u; } v; v.f = f;
    unsigned r = v.u + 0x7fffu + ((v.u >> 16) & 1u);
    return (unsigned short)(r >> 16);
}
__device__ inline unsigned short f2bf_fast(float f) {
    union { float f; unsigned u; } v; v.f = f;
    return (unsigned short)((v.u + 0x8000u) >> 16);
}
__device__ inline float bf2f(short s) {
    union { unsigned u; float f; } v;
    v.u = ((unsigned)(unsigned short)s) << 16;
    return v.f;
}
__device__ inline void async16(const unsigned short* g, short* l) {
    __builtin_amdgcn_global_load_lds(
        (const __attribute__((address_space(1))) unsigned*)g,
        (__attribute__((address_space(3))) unsigned*)l, 16, 0, 0);
}

// ---------------- cast fp32 -> bf16, 4 elems/thread ----------------
__global__ void cast_f32_bf16(const float* __restrict__ in,
                              unsigned short* __restrict__ out, int n4) {
    int i = blockIdx.x * blockDim.x + threadIdx.x;
    if (i < n4) {
        float4 v = ((const float4*)in)[i];
        ushort4 o;
        o.x = f2bf(v.x); o.y = f2bf(v.y); o.z = f2bf(v.z); o.w = f2bf(v.w);
        ((ushort4*)out)[i] = o;
    }
}

// ---------------- 64-tile NT GEMM (narrow N: q/k proj) ----------------
// SWZ=0: bf16 row-major out. SWZ=1: K-swizzled out [tok>>5][hd>>3][tok&31][hd&7]
template<int SWZ>
__global__ __launch_bounds__(256) void gemm_nt(
    const unsigned short* __restrict__ A, const unsigned short* __restrict__ W,
    const float* __restrict__ bias, unsigned short* __restrict__ out, int M, int N, int K)
{
    __shared__ short As[4][64][8];
    __shared__ short Ws[4][64][8];
    const int tid = threadIdx.x;
    const int wave = tid >> 6, lane = tid & 63;
    const int lr = lane & 15, lc = lane >> 4;
    const int m0 = blockIdx.x * 64, n0 = blockIdx.y * 64;

    floatx4 acc[4] = {};
    const int srow = tid >> 2, sch = tid & 3;
    const unsigned short* Ag = A + (long)(m0 + srow) * K + sch * 8;
    const unsigned short* Wg = W + (long)(n0 + srow) * K + sch * 8;

    for (int k0 = 0; k0 < K; k0 += 32) {
        *(short8*)&As[sch][srow][0] = *(const short8*)(Ag + k0);
        *(short8*)&Ws[sch][srow][0] = *(const short8*)(Wg + k0);
        __syncthreads();
        short8 a = *(short8*)&As[lc][wave * 16 + lr][0];
#pragma unroll
        for (int s = 0; s < 4; s++) {
            short8 b = *(short8*)&Ws[lc][s * 16 + lr][0];
            acc[s] = __builtin_amdgcn_mfma_f32_16x16x32_bf16(a, b, acc[s], 0, 0, 0);
        }
        __syncthreads();
    }

#pragma unroll
    for (int s = 0; s < 4; s++) {
        int h = n0 + s * 16 + lr;
        float bv = bias[h];
        int tok0 = m0 + wave * 16 + lc * 4;
#pragma unroll
        for (int r = 0; r < 4; r++) {
            int tok = tok0 + r;
            if (SWZ)
                out[(tok >> 5) * 4096 + (h >> 3) * 256 + (tok & 31) * 8 + (h & 7)] =
                    f2bf(acc[s][r] + bv);
            else
                out[(long)tok * N + h] = f2bf(acc[s][r] + bv);
        }
    }
}

// ---------------- 128-tile NT GEMM, global_load_lds staging ----------------
// MODE 0: f32 out row-major; MODE 2: V-swizzled bf16 out
template<int MODE>
__global__ __launch_bounds__(256) void gemm128_nt(
    const unsigned short* __restrict__ A, const unsigned short* __restrict__ W,
    const float* __restrict__ bias, void* __restrict__ out, int M, int N, int K)
{
    __shared__ short As[128][4][8]; // [row][k-chunk][8]
    __shared__ short Ws[128][4][8];
    const int tid = threadIdx.x, wave = tid >> 6, lane = tid & 63;
    const int lr = lane & 15, lc = lane >> 4;
    const int wm = (wave >> 1) * 64, wn = (wave & 1) * 64;
    const int m0 = blockIdx.x * 128, n0 = blockIdx.y * 128;

    floatx4 acc[4][4] = {};

    const int srow = lane >> 2, sch = lane & 3;
    const unsigned short* Ag0 = A + (long)(m0 + wave * 32 + srow) * K + sch * 8;
    const unsigned short* Ag1 = Ag0 + (long)16 * K;
    const unsigned short* Wg0 = W + (long)(n0 + wave * 32 + srow) * K + sch * 8;
    const unsigned short* Wg1 = Wg0 + (long)16 * K;
    short* lA0 = &As[wave * 32][0][0];
    short* lA1 = &As[wave * 32 + 16][0][0];
    short* lW0 = &Ws[wave * 32][0][0];
    short* lW1 = &Ws[wave * 32 + 16][0][0];

    for (int k0 = 0; k0 < K; k0 += 32) {
        async16(Ag0 + k0, lA0);
        async16(Ag1 + k0, lA1);
        async16(Wg0 + k0, lW0);
        async16(Wg1 + k0, lW1);
        __syncthreads();
        short8 af[4], bfg[4];
#pragma unroll
        for (int i = 0; i < 4; i++) af[i]  = *(short8*)&As[wm + i * 16 + lr][lc][0];
#pragma unroll
        for (int j = 0; j < 4; j++) bfg[j] = *(short8*)&Ws[wn + j * 16 + lr][lc][0];
#pragma unroll
        for (int i = 0; i < 4; i++)
#pragma unroll
            for (int j = 0; j < 4; j++)
                acc[i][j] = __builtin_amdgcn_mfma_f32_16x16x32_bf16(af[i], bfg[j], acc[i][j], 0, 0, 0);
        __syncthreads();
    }

#pragma unroll
    for (int i = 0; i < 4; i++) {
        int t0 = m0 + wm + i * 16 + lc * 4;
#pragma unroll
        for (int j = 0; j < 4; j++) {
            int c = n0 + wn + j * 16 + lr;
            float bv = bias[c];
            if (MODE == 0) {
                float* o = (float*)out;
#pragma unroll
                for (int r = 0; r < 4; r++) o[(long)(t0 + r) * N + c] = acc[i][j][r] + bv;
            } else {
                unsigned short* o = (unsigned short*)out;
                ushort4 pk;
                pk.x = f2bf(acc[i][j][0] + bv); pk.y = f2bf(acc[i][j][1] + bv);
                pk.z = f2bf(acc[i][j][2] + bv); pk.w = f2bf(acc[i][j][3] + bv);
                long off = (long)(c >> 8) * 2097152 + (t0 >> 5) * 8192 +
                           ((t0 & 31) >> 3) * 2048 + (c & 255) * 8 + (t0 & 7);
                *(ushort4*)&o[off] = pk;
            }
        }
    }
}

// ---------------- fused attention: partial O = exp(QK^T*scale) @ V + rowsum ----------------
// grid (m-tiles=32, c-tiles=4, n-split=2); block: 4 waves, each wave 64 q-rows x 256 c.
// ms=4: K/V fragments reused 4x from registers -> 333 B LDS per MFMA (LDS-pipe floor
// ~95us/CU vs 185 at ms=2 -- rounds 2-4 were LDS-BW-bound at ~80% of that pipe).
// Cost: acc[4][16]=256 AGPR -> 1 wave/SIMD; latency covered by the PV(it-1)||QK(it)
// software pipeline (two independent MFMA chains/iter) + one-iter-early staging.
// V triple-buffered, K double-buffered, P single-buffered (WAR-safe in-order).
// K_swz: [ntile32][ch16][row32][8] 8KB; V_swz: [cblk][ntile32][ch4][c256][8] 16KB.
__global__ __launch_bounds__(256, 1) void attn_pv(
    const unsigned short* __restrict__ qb, const unsigned short* __restrict__ ksw,
    const unsigned short* __restrict__ vsw,
    unsigned short* __restrict__ Oa, unsigned short* __restrict__ Ob,
    float* __restrict__ la, float* __restrict__ lb)
{
    __shared__ short Ks[2][16][32][8];   // 16 KB (K double buffer)
    __shared__ short Vs[3][4][256][8];   // 48 KB (V triple buffer)
    __shared__ short Ps[4][64][40];      // 20 KB [wave][m 64][n 32 + pad]

    const int tid = threadIdx.x, wave = tid >> 6, lane = tid & 63;
    const int lr = lane & 15, lc = lane >> 4;
    const int m0 = blockIdx.x * 256, cblk = blockIdx.y;
    const int mw = m0 + wave * 64;
    const int nt0 = blockIdx.z * 128; // in 32-n tiles; 128 iters
    unsigned short* Op = blockIdx.z ? Ob : Oa;
    float* ls = blockIdx.z ? lb : la;
    const float cexp = (float)(0.08838834764831845 * 1.4426950408889634); // scale*log2e

    // Q fragments for 4 m-subtiles (B-operand of S^T mfma)
    short8 qf[4][4];
#pragma unroll
    for (int ms = 0; ms < 4; ms++)
#pragma unroll
        for (int kk = 0; kk < 4; kk++)
            qf[ms][kk] = *(const short8*)&qb[(mw + ms * 16 + lr) * HDIM + kk * 32 + lc * 8];

    floatx4 acc[4][16] = {};
    float lsum[4] = {};

    // staging: every wave-load = 64 lanes x 16 B = 1 KB contiguous
    // K per tile = 8 chunks of 512 shorts -> 2 chunks per wave
    // V per tile = 16 chunks -> 4 chunks per wave
    const unsigned short* kg[2];
    short* const klb = &Ks[0][0][0][0];
#pragma unroll
    for (int t = 0; t < 2; t++) kg[t] = ksw + (wave * 2 + t) * 512 + lane * 8;
    const unsigned short* vg[4];
#pragma unroll
    for (int t = 0; t < 4; t++)
        vg[t] = vsw + (long)cblk * 2097152 + (wave * 4 + t) * 512 + lane * 8;

    // V slot rotation: v_r = V(it-1) [PV source], v_m = V(it), v_w = stage dest V(it+1).
    short* v_r = &Vs[2][0][0][0];
    short* v_m = &Vs[0][0][0][0];
    short* v_w = &Vs[1][0][0][0];

    // prologue: stage tile 0 (K->Ks[0], V->slot0)
    {
        long nt = nt0;
#pragma unroll
        for (int t = 0; t < 2; t++)
            async16(kg[t] + nt * 4096, klb + (wave * 2 + t) * 512);
#pragma unroll
        for (int t = 0; t < 4; t++)
            async16(vg[t] + nt * 8192, v_m + (wave * 4 + t) * 512);
    }

    for (int it = 0; it < 128; ++it) {
        const int buf = it & 1;
        __syncthreads(); // tile(it) staged; all waves done with old slots
        if (it + 1 < 128) {
            long nt = nt0 + it + 1;
#pragma unroll
            for (int t = 0; t < 2; t++)
                async16(kg[t] + nt * 4096, klb + (buf ^ 1) * 4096 + (wave * 2 + t) * 512);
#pragma unroll
            for (int t = 0; t < 4; t++)
                async16(vg[t] + nt * 8192, v_w + (wave * 4 + t) * 512);
        }

        // ---- PV(it-1): O += P(it-1) @ V(it-1); independent of this tile's QK chain ----
        if (it > 0) {
            short8 ap[4];
#pragma unroll
            for (int ms = 0; ms < 4; ms++) ap[ms] = *(short8*)&Ps[wave][ms * 16 + lr][lc * 8];
#pragma unroll
            for (int csh = 0; csh < 2; csh++) {
                short8 bv[8];
#pragma unroll
                for (int cs = 0; cs < 8; cs++)
                    bv[cs] = *(short8*)(v_r + lc * 2048 + ((csh * 8 + cs) * 16 + lr) * 8);
#pragma unroll
                for (int ms = 0; ms < 4; ms++)
#pragma unroll
                    for (int cs = 0; cs < 8; cs++)
                        acc[ms][csh * 8 + cs] =
                            __builtin_amdgcn_mfma_f32_16x16x32_bf16(ap[ms], bv[cs], acc[ms][csh * 8 + cs], 0, 0, 0);
            }
        }

        // ---- QK^T(it): st[ms][sub] = K[n-sub] @ Q[ms]^T ; q-row=lr, n=sub*16+lc*4+r ----
        floatx4 st[4][2] = {};
#pragma unroll
        for (int kk = 0; kk < 4; kk++) {
            short8 kf0 = *(short8*)&Ks[buf][kk * 4 + lc][lr][0];
            short8 kf1 = *(short8*)&Ks[buf][kk * 4 + lc][16 + lr][0];
#pragma unroll
            for (int ms = 0; ms < 4; ms++) {
                st[ms][0] = __builtin_amdgcn_mfma_f32_16x16x32_bf16(kf0, qf[ms][kk], st[ms][0], 0, 0, 0);
                st[ms][1] = __builtin_amdgcn_mfma_f32_16x16x32_bf16(kf1, qf[ms][kk], st[ms][1], 0, 0, 0);
            }
        }

        // ---- P(it) = exp2(st*c): packed writes (after ap-read above: WAR-safe in-order) ----
#pragma unroll
        for (int ms = 0; ms < 4; ms++)
#pragma unroll
            for (int sub = 0; sub < 2; sub++) {
                ushort4v pk;
#pragma unroll
                for (int r = 0; r < 4; r++) {
                    float p = __builtin_amdgcn_exp2f(st[ms][sub][r] * cexp);
                    lsum[ms] += p;
                    pk[r] = f2bf_fast(p);
                }
                *(ushort4v*)&Ps[wave][ms * 16 + lr][sub * 16 + lc * 4] = pk;
            }

        // rotate V slots
        short* tmp = v_r; v_r = v_m; v_m = v_w; v_w = tmp;
    }

    // epilogue: PV(127) -- P in own-wave Ps, V(127) in v_r after final rotation
    {
        short8 ap[4];
#pragma unroll
        for (int ms = 0; ms < 4; ms++) ap[ms] = *(short8*)&Ps[wave][ms * 16 + lr][lc * 8];
#pragma unroll
        for (int csh = 0; csh < 2; csh++) {
            short8 bv[8];
#pragma unroll
            for (int cs = 0; cs < 8; cs++)
                bv[cs] = *(short8*)(v_r + lc * 2048 + ((csh * 8 + cs) * 16 + lr) * 8);
#pragma unroll
            for (int ms = 0; ms < 4; ms++)
#pragma unroll
                for (int cs = 0; cs < 8; cs++)
                    acc[ms][csh * 8 + cs] =
                        __builtin_amdgcn_mfma_f32_16x16x32_bf16(ap[ms], bv[cs], acc[ms][csh * 8 + cs], 0, 0, 0);
        }
    }

    // unnormalized partial O
#pragma unroll
    for (int ms = 0; ms < 4; ms++)
#pragma unroll
        for (int cs = 0; cs < 16; cs++) {
            int c = cblk * 256 + cs * 16 + lr;
#pragma unroll
            for (int r = 0; r < 4; r++)
                Op[(long)(mw + ms * 16 + lc * 4 + r) * CDIM + c] = f2bf(acc[ms][cs][r]);
        }
    // partial row sums (q-row = ms*16+lr; reduce over lc lanes)
    if (blockIdx.y == 0) {
#pragma unroll
        for (int ms = 0; ms < 4; ms++) {
            lsum[ms] += __shfl_xor(lsum[ms], 16);
            lsum[ms] += __shfl_xor(lsum[ms], 32);
        }
        if (lc == 0) {
#pragma unroll
            for (int ms = 0; ms < 4; ms++) ls[mw + ms * 16 + lr] = lsum[ms];
        }
    }
}

// ---------------- combine: attn = (Oa + Ob) / (la + lb), in place over Ob ----------------
__global__ __launch_bounds__(256) void combine_attn(
    const unsigned short* __restrict__ Oa, unsigned short* __restrict__ Ob,
    const float* __restrict__ la, const float* __restrict__ lb)
{
    int i = blockIdx.x * blockDim.x + threadIdx.x; // one per 8 elems
    int row = i >> 7;                              // CDIM/8 = 128
    float inv = 1.0f / (la[row] + lb[row]);
    short8 a = ((const short8*)Oa)[i];
    short8 b = ((const short8*)Ob)[i];
    short8 o;
#pragma unroll
    for (int e = 0; e < 8; e++) o[e] = (short)f2bf((bf2f(a[e]) + bf2f(b[e])) * inv);
    ((short8*)Ob)[i] = o;
}

extern "C" void kernel_launch(void* const* d_in, const int* in_sizes, int n_in,
                              void* d_out, int out_size, void* d_ws, size_t ws_size,
                              hipStream_t stream) {
    const float* x  = (const float*)d_in[0];
    const float* Wq = (const float*)d_in[1];
    const float* bq = (const float*)d_in[2];
    const float* Wk = (const float*)d_in[3];
    const float* bk = (const float*)d_in[4];
    const float* Wv = (const float*)d_in[5];
    const float* bv = (const float*)d_in[6];
    const float* Wo = (const float*)d_in[7];
    const float* bo = (const float*)d_in[8];

    char* ws = (char*)d_ws;
    unsigned short* x_bf   = (unsigned short*)(ws + 0);          // 16 MB (reused as Oa)
    unsigned short* wq_bf  = (unsigned short*)(ws + 16777216);   // 256 KB
    unsigned short* wk_bf  = (unsigned short*)(ws + 17039360);   // 256 KB
    unsigned short* wv_bf  = (unsigned short*)(ws + 17301504);   // 2 MB
    unsigned short* wo_bf  = (unsigned short*)(ws + 19398656);   // 2 MB
    unsigned short* q_bf   = (unsigned short*)(ws + 21495808);   // 2 MB
    unsigned short* k_swz  = (unsigned short*)(ws + 23592960);   // 2 MB (K swizzled)
    unsigned short* v_swz  = (unsigned short*)(ws + 25690112);   // 16 MB (V swizzled)
    unsigned short* attn_bf= (unsigned short*)(ws + 42467328);   // 16 MB (Ob, combined in place)
    float* lsum_a          = (float*)(ws + 59244544);            // 32 KB
    float* lsum_b          = (float*)(ws + 59277312);            // 32 KB

    // casts to bf16
    cast_f32_bf16<<<8192, 256, 0, stream>>>(x,  x_bf,  2097152);
    cast_f32_bf16<<<128,  256, 0, stream>>>(Wq, wq_bf, 32768);
    cast_f32_bf16<<<128,  256, 0, stream>>>(Wk, wk_bf, 32768);
    cast_f32_bf16<<<1024, 256, 0, stream>>>(Wv, wv_bf, 262144);
    cast_f32_bf16<<<1024, 256, 0, stream>>>(Wo, wo_bf, 262144);

    // projections
    gemm_nt<0><<<dim3(128, 2), 256, 0, stream>>>(x_bf, wq_bf, bq, q_bf, NTOK, HDIM, CDIM);
    gemm_nt<1><<<dim3(128, 2), 256, 0, stream>>>(x_bf, wk_bf, bk, k_swz, NTOK, HDIM, CDIM);
    gemm128_nt<2><<<dim3(64, 8), 256, 0, stream>>>(x_bf, wv_bf, bv, v_swz, NTOK, CDIM, CDIM);

    // fused attention (split-n over gridDim.z); Oa overlays dead x_bf
    attn_pv<<<dim3(32, 4, 2), 256, 0, stream>>>(q_bf, k_swz, v_swz,
                                                x_bf, attn_bf, lsum_a, lsum_b);
    combine_attn<<<4096, 256, 0, stream>>>(x_bf, attn_bf, lsum_a, lsum_b);

    // output projection (fp32 out)
    gemm128_nt<0><<<dim3(64, 8), 256, 0, stream>>>(attn_bf, wo_bf, bo, d_out, NTOK, CDIM, CDIM);
}

// Round 6
// 400.068 us; speedup vs baseline: 1.2865x; 1.2865x over previous
//
#include <hip/hip_runtime.h>

#define NTOK 8192
#define CDIM 1024
#define HDIM 128

typedef __attribute__((ext_vector_type(8))) short short8;
typedef __attribute__((ext_vector_type(4))) float floatx4;
typedef __attribute__((ext_vector_type(16))) float floatx16;
typedef __attribute__((ext_vector_type(4))) unsigned short ushort4v;

__device__ inline unsigned short f2bf(float f) {
    union { float f; unsigned u; } v; v.f = f;
    unsigned r = v.u + 0x7fffu + ((v.u >> 16) & 1u);
    return (unsigned short)(r >> 16);
}
__device__ inline float bf2f(short s) {
    union { unsigned u; float f; } v;
    v.u = ((unsigned)(unsigned short)s) << 16;
    return v.f;
}
__device__ inline void async16(const unsigned short* g, short* l) {
    __builtin_amdgcn_global_load_lds(
        (const __attribute__((address_space(1))) unsigned*)g,
        (__attribute__((address_space(3))) unsigned*)l, 16, 0, 0);
}

// ---------------- cast fp32 -> bf16, 4 elems/thread ----------------
__global__ void cast_f32_bf16(const float* __restrict__ in,
                              unsigned short* __restrict__ out, int n4) {
    int i = blockIdx.x * blockDim.x + threadIdx.x;
    if (i < n4) {
        float4 v = ((const float4*)in)[i];
        ushort4 o;
        o.x = f2bf(v.x); o.y = f2bf(v.y); o.z = f2bf(v.z); o.w = f2bf(v.w);
        ((ushort4*)out)[i] = o;
    }
}

// ---------------- 64-tile NT GEMM (narrow N: q/k proj) ----------------
// SWZ=0: bf16 row-major out. SWZ=1: K-swizzled out [tok>>5][hd>>3][tok&31][hd&7]
template<int SWZ>
__global__ __launch_bounds__(256) void gemm_nt(
    const unsigned short* __restrict__ A, const unsigned short* __restrict__ W,
    const float* __restrict__ bias, unsigned short* __restrict__ out, int M, int N, int K)
{
    __shared__ short As[4][64][8];
    __shared__ short Ws[4][64][8];
    const int tid = threadIdx.x;
    const int wave = tid >> 6, lane = tid & 63;
    const int lr = lane & 15, lc = lane >> 4;
    const int m0 = blockIdx.x * 64, n0 = blockIdx.y * 64;

    floatx4 acc[4] = {};
    const int srow = tid >> 2, sch = tid & 3;
    const unsigned short* Ag = A + (long)(m0 + srow) * K + sch * 8;
    const unsigned short* Wg = W + (long)(n0 + srow) * K + sch * 8;

    for (int k0 = 0; k0 < K; k0 += 32) {
        *(short8*)&As[sch][srow][0] = *(const short8*)(Ag + k0);
        *(short8*)&Ws[sch][srow][0] = *(const short8*)(Wg + k0);
        __syncthreads();
        short8 a = *(short8*)&As[lc][wave * 16 + lr][0];
#pragma unroll
        for (int s = 0; s < 4; s++) {
            short8 b = *(short8*)&Ws[lc][s * 16 + lr][0];
            acc[s] = __builtin_amdgcn_mfma_f32_16x16x32_bf16(a, b, acc[s], 0, 0, 0);
        }
        __syncthreads();
    }

#pragma unroll
    for (int s = 0; s < 4; s++) {
        int h = n0 + s * 16 + lr;
        float bv = bias[h];
        int tok0 = m0 + wave * 16 + lc * 4;
#pragma unroll
        for (int r = 0; r < 4; r++) {
            int tok = tok0 + r;
            if (SWZ)
                out[(tok >> 5) * 4096 + (h >> 3) * 256 + (tok & 31) * 8 + (h & 7)] =
                    f2bf(acc[s][r] + bv);
            else
                out[(long)tok * N + h] = f2bf(acc[s][r] + bv);
        }
    }
}

// ---------------- 128-tile NT GEMM, global_load_lds staging ----------------
// MODE 0: f32 out row-major; MODE 2: V-swizzled bf16 out
template<int MODE>
__global__ __launch_bounds__(256) void gemm128_nt(
    const unsigned short* __restrict__ A, const unsigned short* __restrict__ W,
    const float* __restrict__ bias, void* __restrict__ out, int M, int N, int K)
{
    __shared__ short As[128][4][8]; // [row][k-chunk][8]
    __shared__ short Ws[128][4][8];
    const int tid = threadIdx.x, wave = tid >> 6, lane = tid & 63;
    const int lr = lane & 15, lc = lane >> 4;
    const int wm = (wave >> 1) * 64, wn = (wave & 1) * 64;
    const int m0 = blockIdx.x * 128, n0 = blockIdx.y * 128;

    floatx4 acc[4][4] = {};

    const int srow = lane >> 2, sch = lane & 3;
    const unsigned short* Ag0 = A + (long)(m0 + wave * 32 + srow) * K + sch * 8;
    const unsigned short* Ag1 = Ag0 + (long)16 * K;
    const unsigned short* Wg0 = W + (long)(n0 + wave * 32 + srow) * K + sch * 8;
    const unsigned short* Wg1 = Wg0 + (long)16 * K;
    short* lA0 = &As[wave * 32][0][0];
    short* lA1 = &As[wave * 32 + 16][0][0];
    short* lW0 = &Ws[wave * 32][0][0];
    short* lW1 = &Ws[wave * 32 + 16][0][0];

    for (int k0 = 0; k0 < K; k0 += 32) {
        async16(Ag0 + k0, lA0);
        async16(Ag1 + k0, lA1);
        async16(Wg0 + k0, lW0);
        async16(Wg1 + k0, lW1);
        __syncthreads();
        short8 af[4], bfg[4];
#pragma unroll
        for (int i = 0; i < 4; i++) af[i]  = *(short8*)&As[wm + i * 16 + lr][lc][0];
#pragma unroll
        for (int j = 0; j < 4; j++) bfg[j] = *(short8*)&Ws[wn + j * 16 + lr][lc][0];
#pragma unroll
        for (int i = 0; i < 4; i++)
#pragma unroll
            for (int j = 0; j < 4; j++)
                acc[i][j] = __builtin_amdgcn_mfma_f32_16x16x32_bf16(af[i], bfg[j], acc[i][j], 0, 0, 0);
        __syncthreads();
    }

#pragma unroll
    for (int i = 0; i < 4; i++) {
        int t0 = m0 + wm + i * 16 + lc * 4;
#pragma unroll
        for (int j = 0; j < 4; j++) {
            int c = n0 + wn + j * 16 + lr;
            float bv = bias[c];
            if (MODE == 0) {
                float* o = (float*)out;
#pragma unroll
                for (int r = 0; r < 4; r++) o[(long)(t0 + r) * N + c] = acc[i][j][r] + bv;
            } else {
                unsigned short* o = (unsigned short*)out;
                ushort4 pk;
                pk.x = f2bf(acc[i][j][0] + bv); pk.y = f2bf(acc[i][j][1] + bv);
                pk.z = f2bf(acc[i][j][2] + bv); pk.w = f2bf(acc[i][j][3] + bv);
                long off = (long)(c >> 8) * 2097152 + (t0 >> 5) * 8192 +
                           ((t0 & 31) >> 3) * 2048 + (c & 255) * 8 + (t0 & 7);
                *(ushort4*)&o[off] = pk;
            }
        }
    }
}

// ---------------- fused attention: partial O = exp(QK^T*scale) @ V + rowsum ----------------
// grid (m-tiles=64, c-tiles=4, n-split=2); block: 4 waves, each wave 32 q-rows x 256 c.
// 32x32x16 MFMA both stages; P entirely IN REGISTERS: QK^T C-layout (col=lane&31=q,
// row=n=(r&3)+8(r>>2)+4(lane>>5)) is one permlane32_swap away from the PV A-operand
// layout (row=lane&31, k=(lane>>5)*8+e). 8 cvt_pk + 4 permlane replace the LDS P
// round-trip (4KB/wave-iter) + its lgkm serialization. LDS = K db 16KB + V db 32KB
// = 48KB -> 2 independent blocks/CU, 2 waves/SIMD (reg cap). setprio(1) on MFMA
// clusters (T5; role diversity from de-correlated blocks).
// K_swz: [ntile32][ch16][row32][8] 8KB; V_swz: [cblk][ntile32][ch4][c256][8] 16KB.
__global__ __launch_bounds__(256, 2) void attn_pv(
    const unsigned short* __restrict__ qb, const unsigned short* __restrict__ ksw,
    const unsigned short* __restrict__ vsw,
    unsigned short* __restrict__ Oa, unsigned short* __restrict__ Ob,
    float* __restrict__ la, float* __restrict__ lb)
{
    __shared__ short Ks[2][16][32][8];  // 16 KB (K double buffer)
    __shared__ short Vs[2][4][256][8];  // 32 KB (V double buffer)

    const int tid = threadIdx.x, wave = tid >> 6, lane = tid & 63;
    const int l31 = lane & 31, h = lane >> 5;
    const int m0 = blockIdx.x * 128, cblk = blockIdx.y;
    const int mw = m0 + wave * 32;
    const int nt0 = blockIdx.z * 128; // in 32-n tiles; 128 iters
    unsigned short* Op = blockIdx.z ? Ob : Oa;
    float* ls = blockIdx.z ? lb : la;
    const float cexp = (float)(0.08838834764831845 * 1.4426950408889634); // scale*log2e

    // Q fragments: B-operand of 32x32x16 (col=q=lane&31, k=d=(lane>>5)*8+e), 8 k-steps
    short8 qf[8];
#pragma unroll
    for (int kk = 0; kk < 8; kk++)
        qf[kk] = *(const short8*)&qb[(mw + l31) * HDIM + kk * 16 + h * 8];

    floatx16 acc[8] = {};
    float lsum = 0.f;

    // staging: every wave-load = 64 lanes x 16 B = 1 KB contiguous
    // K per tile = 8 chunks of 512 shorts -> 2 chunks per wave
    // V per tile = 16 chunks -> 4 chunks per wave
    const unsigned short* kg[2];
    short* const klb = &Ks[0][0][0][0];
#pragma unroll
    for (int t = 0; t < 2; t++) kg[t] = ksw + (wave * 2 + t) * 512 + lane * 8;
    const unsigned short* vg[4];
    short* const vlb = &Vs[0][0][0][0];
#pragma unroll
    for (int t = 0; t < 4; t++)
        vg[t] = vsw + (long)cblk * 2097152 + (wave * 4 + t) * 512 + lane * 8;

    // prologue: stage tile 0 into buf 0
    {
        long nt = nt0;
#pragma unroll
        for (int t = 0; t < 2; t++)
            async16(kg[t] + nt * 4096, klb + (wave * 2 + t) * 512);
#pragma unroll
        for (int t = 0; t < 4; t++)
            async16(vg[t] + nt * 8192, vlb + (wave * 4 + t) * 512);
    }

    for (int it = 0; it < 128; ++it) {
        const int buf = it & 1;
        __syncthreads(); // drains vmem -> buf ready; all waves done with buf^1
        if (it + 1 < 128) {
            long nt = nt0 + it + 1;
#pragma unroll
            for (int t = 0; t < 2; t++)
                async16(kg[t] + nt * 4096, klb + (buf ^ 1) * 4096 + (wave * 2 + t) * 512);
#pragma unroll
            for (int t = 0; t < 4; t++)
                async16(vg[t] + nt * 8192,
                        vlb + (buf ^ 1) * 8192 + (wave * 4 + t) * 512);
        }

        // ---- QK^T: S^T[32n x 32q] = K-tile @ Q^T (A=K: row=n=lane&31, k=d) ----
        floatx16 st = {};
        __builtin_amdgcn_s_setprio(1);
#pragma unroll
        for (int kk = 0; kk < 8; kk++) {
            short8 kf = *(short8*)&Ks[buf][kk * 2 + h][l31][0];
            st = __builtin_amdgcn_mfma_f32_32x32x16_bf16(kf, qf[kk], st, 0, 0, 0);
        }
        __builtin_amdgcn_s_setprio(0);

        // ---- P = exp2(st*c): lane holds P[q=l31][16 n-values]; pack consecutive-n
        // pairs (regs 2i,2i+1) to bf16x2 dwords ----
        unsigned pk0, pk1, pk2, pk3, pk4, pk5, pk6, pk7;
        {
            float p0, p1;
#define PK(I, DST) \
            p0 = __builtin_amdgcn_exp2f(st[2 * I] * cexp); \
            p1 = __builtin_amdgcn_exp2f(st[2 * I + 1] * cexp); \
            lsum += p0 + p1; \
            asm("v_cvt_pk_bf16_f32 %0, %1, %2" : "=v"(DST) : "v"(p0), "v"(p1));
            PK(0, pk0) PK(1, pk1) PK(2, pk2) PK(3, pk3)
            PK(4, pk4) PK(5, pk5) PK(6, pk6) PK(7, pk7)
#undef PK
        }
        // permlane32_swap: a' = {a.lo-lanes keep, hi-lanes get b.lo-vals},
        //                  b' = {lo-lanes get a.hi-vals, hi-lanes keep b}.
        // After swaps: (pk0..pk3) = A-frag k-step0 dwords, (pk4..pk7) = k-step1.
        asm("v_permlane32_swap_b32 %0, %1" : "+v"(pk0), "+v"(pk2));
        asm("v_permlane32_swap_b32 %0, %1" : "+v"(pk1), "+v"(pk3));
        asm("v_permlane32_swap_b32 %0, %1" : "+v"(pk4), "+v"(pk6));
        asm("v_permlane32_swap_b32 %0, %1" : "+v"(pk5), "+v"(pk7));
        union { unsigned u[4]; short8 s; } up0, up1;
        up0.u[0] = pk0; up0.u[1] = pk1; up0.u[2] = pk2; up0.u[3] = pk3;
        up1.u[0] = pk4; up1.u[1] = pk5; up1.u[2] = pk6; up1.u[3] = pk7;
        const short8 pa0 = up0.s, pa1 = up1.s;

        // ---- PV: O[32q x 256c] += P[32 x 32] @ V[32 x 256] (B=V: col=c=lane&31, k=n) ----
        __builtin_amdgcn_s_setprio(1);
#pragma unroll
        for (int ct = 0; ct < 8; ct++) {
            short8 bv0 = *(short8*)&Vs[buf][h][ct * 32 + l31][0];
            short8 bv1 = *(short8*)&Vs[buf][2 + h][ct * 32 + l31][0];
            acc[ct] = __builtin_amdgcn_mfma_f32_32x32x16_bf16(pa0, bv0, acc[ct], 0, 0, 0);
            acc[ct] = __builtin_amdgcn_mfma_f32_32x32x16_bf16(pa1, bv1, acc[ct], 0, 0, 0);
        }
        __builtin_amdgcn_s_setprio(0);
    }

    // unnormalized partial O: q = (r&3)+8*(r>>2)+4*h, c = cblk*256 + ct*32 + l31
#pragma unroll
    for (int ct = 0; ct < 8; ct++) {
        int c = cblk * 256 + ct * 32 + l31;
#pragma unroll
        for (int r = 0; r < 16; r++) {
            int q = (r & 3) + 8 * (r >> 2) + 4 * h;
            Op[(long)(mw + q) * CDIM + c] = f2bf(acc[ct][r]);
        }
    }
    // partial row sums: lane q=l31 holds 16 of 32 n per tile; partner (lane^32) the rest
    if (blockIdx.y == 0) {
        lsum += __shfl_xor(lsum, 32);
        if (lane < 32) ls[mw + lane] = lsum;
    }
}

// ---------------- combine: attn = (Oa + Ob) / (la + lb), in place over Ob ----------------
__global__ __launch_bounds__(256) void combine_attn(
    const unsigned short* __restrict__ Oa, unsigned short* __restrict__ Ob,
    const float* __restrict__ la, const float* __restrict__ lb)
{
    int i = blockIdx.x * blockDim.x + threadIdx.x; // one per 8 elems
    int row = i >> 7;                              // CDIM/8 = 128
    float inv = 1.0f / (la[row] + lb[row]);
    short8 a = ((const short8*)Oa)[i];
    short8 b = ((const short8*)Ob)[i];
    short8 o;
#pragma unroll
    for (int e = 0; e < 8; e++) o[e] = (short)f2bf((bf2f(a[e]) + bf2f(b[e])) * inv);
    ((short8*)Ob)[i] = o;
}

extern "C" void kernel_launch(void* const* d_in, const int* in_sizes, int n_in,
                              void* d_out, int out_size, void* d_ws, size_t ws_size,
                              hipStream_t stream) {
    const float* x  = (const float*)d_in[0];
    const float* Wq = (const float*)d_in[1];
    const float* bq = (const float*)d_in[2];
    const float* Wk = (const float*)d_in[3];
    const float* bk = (const float*)d_in[4];
    const float* Wv = (const float*)d_in[5];
    const float* bv = (const float*)d_in[6];
    const float* Wo = (const float*)d_in[7];
    const float* bo = (const float*)d_in[8];

    char* ws = (char*)d_ws;
    unsigned short* x_bf   = (unsigned short*)(ws + 0);          // 16 MB (reused as Oa)
    unsigned short* wq_bf  = (unsigned short*)(ws + 16777216);   // 256 KB
    unsigned short* wk_bf  = (unsigned short*)(ws + 17039360);   // 256 KB
    unsigned short* wv_bf  = (unsigned short*)(ws + 17301504);   // 2 MB
    unsigned short* wo_bf  = (unsigned short*)(ws + 19398656);   // 2 MB
    unsigned short* q_bf   = (unsigned short*)(ws + 21495808);   // 2 MB
    unsigned short* k_swz  = (unsigned short*)(ws + 23592960);   // 2 MB (K swizzled)
    unsigned short* v_swz  = (unsigned short*)(ws + 25690112);   // 16 MB (V swizzled)
    unsigned short* attn_bf= (unsigned short*)(ws + 42467328);   // 16 MB (Ob, combined in place)
    float* lsum_a          = (float*)(ws + 59244544);            // 32 KB
    float* lsum_b          = (float*)(ws + 59277312);            // 32 KB

    // casts to bf16
    cast_f32_bf16<<<8192, 256, 0, stream>>>(x,  x_bf,  2097152);
    cast_f32_bf16<<<128,  256, 0, stream>>>(Wq, wq_bf, 32768);
    cast_f32_bf16<<<128,  256, 0, stream>>>(Wk, wk_bf, 32768);
    cast_f32_bf16<<<1024, 256, 0, stream>>>(Wv, wv_bf, 262144);
    cast_f32_bf16<<<1024, 256, 0, stream>>>(Wo, wo_bf, 262144);

    // projections
    gemm_nt<0><<<dim3(128, 2), 256, 0, stream>>>(x_bf, wq_bf, bq, q_bf, NTOK, HDIM, CDIM);
    gemm_nt<1><<<dim3(128, 2), 256, 0, stream>>>(x_bf, wk_bf, bk, k_swz, NTOK, HDIM, CDIM);
    gemm128_nt<2><<<dim3(64, 8), 256, 0, stream>>>(x_bf, wv_bf, bv, v_swz, NTOK, CDIM, CDIM);

    // fused attention (split-n over gridDim.z); Oa overlays dead x_bf
    attn_pv<<<dim3(64, 4, 2), 256, 0, stream>>>(q_bf, k_swz, v_swz,
                                                x_bf, attn_bf, lsum_a, lsum_b);
    combine_attn<<<4096, 256, 0, stream>>>(x_bf, attn_bf, lsum_a, lsum_b);

    // output projection (fp32 out)
    gemm128_nt<0><<<dim3(64, 8), 256, 0, stream>>>(attn_bf, wo_bf, bo, d_out, NTOK, CDIM, CDIM);
}

// Round 8
// 396.104 us; speedup vs baseline: 1.2993x; 1.0100x over previous
//
#include <hip/hip_runtime.h>

#define NTOK 8192
#define CDIM 1024
#define HDIM 128

typedef __attribute__((ext_vector_type(8))) short short8;
typedef __attribute__((ext_vector_type(4))) float floatx4;
typedef __attribute__((ext_vector_type(16))) float floatx16;

__device__ inline unsigned short f2bf(float f) {
    union { float f; unsigned u; } v; v.f = f;
    unsigned r = v.u + 0x7fffu + ((v.u >> 16) & 1u);
    return (unsigned short)(r >> 16);
}
__device__ inline float bf2f(short s) {
    union { unsigned u; float f; } v;
    v.u = ((unsigned)(unsigned short)s) << 16;
    return v.f;
}
__device__ inline void async16(const unsigned short* g, short* l) {
    __builtin_amdgcn_global_load_lds(
        (const __attribute__((address_space(1))) unsigned*)g,
        (__attribute__((address_space(3))) unsigned*)l, 16, 0, 0);
}

// ---------------- cast fp32 -> bf16, 4 elems/thread ----------------
__global__ void cast_f32_bf16(const float* __restrict__ in,
                              unsigned short* __restrict__ out, int n4) {
    int i = blockIdx.x * blockDim.x + threadIdx.x;
    if (i < n4) {
        float4 v = ((const float4*)in)[i];
        ushort4 o;
        o.x = f2bf(v.x); o.y = f2bf(v.y); o.z = f2bf(v.z); o.w = f2bf(v.w);
        ((ushort4*)out)[i] = o;
    }
}

// ---------------- 64-tile NT GEMM (narrow N: q/k proj) ----------------
// SWZ=0: bf16 row-major out. SWZ=1: K-swizzled out [tok>>5][hd>>3][tok&31][hd&7]
template<int SWZ>
__global__ __launch_bounds__(256) void gemm_nt(
    const unsigned short* __restrict__ A, const unsigned short* __restrict__ W,
    const float* __restrict__ bias, unsigned short* __restrict__ out, int M, int N, int K)
{
    __shared__ short As[4][64][8];
    __shared__ short Ws[4][64][8];
    const int tid = threadIdx.x;
    const int wave = tid >> 6, lane = tid & 63;
    const int lr = lane & 15, lc = lane >> 4;
    const int m0 = blockIdx.x * 64, n0 = blockIdx.y * 64;

    floatx4 acc[4] = {};
    const int srow = tid >> 2, sch = tid & 3;
    const unsigned short* Ag = A + (long)(m0 + srow) * K + sch * 8;
    const unsigned short* Wg = W + (long)(n0 + srow) * K + sch * 8;

    for (int k0 = 0; k0 < K; k0 += 32) {
        *(short8*)&As[sch][srow][0] = *(const short8*)(Ag + k0);
        *(short8*)&Ws[sch][srow][0] = *(const short8*)(Wg + k0);
        __syncthreads();
        short8 a = *(short8*)&As[lc][wave * 16 + lr][0];
#pragma unroll
        for (int s = 0; s < 4; s++) {
            short8 b = *(short8*)&Ws[lc][s * 16 + lr][0];
            acc[s] = __builtin_amdgcn_mfma_f32_16x16x32_bf16(a, b, acc[s], 0, 0, 0);
        }
        __syncthreads();
    }

#pragma unroll
    for (int s = 0; s < 4; s++) {
        int h = n0 + s * 16 + lr;
        float bv = bias[h];
        int tok0 = m0 + wave * 16 + lc * 4;
#pragma unroll
        for (int r = 0; r < 4; r++) {
            int tok = tok0 + r;
            if (SWZ)
                out[(tok >> 5) * 4096 + (h >> 3) * 256 + (tok & 31) * 8 + (h & 7)] =
                    f2bf(acc[s][r] + bv);
            else
                out[(long)tok * N + h] = f2bf(acc[s][r] + bv);
        }
    }
}

// ---------------- 128-tile NT GEMM, global_load_lds staging ----------------
// MODE 0: f32 out row-major; MODE 2: V-swizzled bf16 out
template<int MODE>
__global__ __launch_bounds__(256) void gemm128_nt(
    const unsigned short* __restrict__ A, const unsigned short* __restrict__ W,
    const float* __restrict__ bias, void* __restrict__ out, int M, int N, int K)
{
    __shared__ short As[128][4][8]; // [row][k-chunk][8]
    __shared__ short Ws[128][4][8];
    const int tid = threadIdx.x, wave = tid >> 6, lane = tid & 63;
    const int lr = lane & 15, lc = lane >> 4;
    const int wm = (wave >> 1) * 64, wn = (wave & 1) * 64;
    const int m0 = blockIdx.x * 128, n0 = blockIdx.y * 128;

    floatx4 acc[4][4] = {};

    const int srow = lane >> 2, sch = lane & 3;
    const unsigned short* Ag0 = A + (long)(m0 + wave * 32 + srow) * K + sch * 8;
    const unsigned short* Ag1 = Ag0 + (long)16 * K;
    const unsigned short* Wg0 = W + (long)(n0 + wave * 32 + srow) * K + sch * 8;
    const unsigned short* Wg1 = Wg0 + (long)16 * K;
    short* lA0 = &As[wave * 32][0][0];
    short* lA1 = &As[wave * 32 + 16][0][0];
    short* lW0 = &Ws[wave * 32][0][0];
    short* lW1 = &Ws[wave * 32 + 16][0][0];

    for (int k0 = 0; k0 < K; k0 += 32) {
        async16(Ag0 + k0, lA0);
        async16(Ag1 + k0, lA1);
        async16(Wg0 + k0, lW0);
        async16(Wg1 + k0, lW1);
        __syncthreads();
        short8 af[4], bfg[4];
#pragma unroll
        for (int i = 0; i < 4; i++) af[i]  = *(short8*)&As[wm + i * 16 + lr][lc][0];
#pragma unroll
        for (int j = 0; j < 4; j++) bfg[j] = *(short8*)&Ws[wn + j * 16 + lr][lc][0];
#pragma unroll
        for (int i = 0; i < 4; i++)
#pragma unroll
            for (int j = 0; j < 4; j++)
                acc[i][j] = __builtin_amdgcn_mfma_f32_16x16x32_bf16(af[i], bfg[j], acc[i][j], 0, 0, 0);
        __syncthreads();
    }

#pragma unroll
    for (int i = 0; i < 4; i++) {
        int t0 = m0 + wm + i * 16 + lc * 4;
#pragma unroll
        for (int j = 0; j < 4; j++) {
            int c = n0 + wn + j * 16 + lr;
            float bv = bias[c];
            if (MODE == 0) {
                float* o = (float*)out;
#pragma unroll
                for (int r = 0; r < 4; r++) o[(long)(t0 + r) * N + c] = acc[i][j][r] + bv;
            } else {
                unsigned short* o = (unsigned short*)out;
                ushort4 pk;
                pk.x = f2bf(acc[i][j][0] + bv); pk.y = f2bf(acc[i][j][1] + bv);
                pk.z = f2bf(acc[i][j][2] + bv); pk.w = f2bf(acc[i][j][3] + bv);
                long off = (long)(c >> 8) * 2097152 + (t0 >> 5) * 8192 +
                           ((t0 & 31) >> 3) * 2048 + (c & 255) * 8 + (t0 & 7);
                *(ushort4*)&o[off] = pk;
            }
        }
    }
}

// ---------------- fused attention: partial O = exp(QK^T*scale) @ V + rowsum ----------------
// grid (m-tiles=64, c-tiles=4, n-split=2); block: 4 waves, each wave 32 q-rows x 256 c.
// 32x32x16 MFMA both stages; P in registers via cvt_pk + permlane32_swap (round 6).
// ROUND 7/8: T3/T4 counted-vmcnt pipeline. Raw s_barrier + "s_waitcnt vmcnt(6)" replaces
// __syncthreads (which drained vmcnt to 0 for all 8 waves/CU, 128x). K/V TRIPLE-buffered;
// tile it+2 staged at iter it -> loads get 2 compute-iterations to land, and one tile of
// loads stays in flight across every barrier. Correctness: 6 loads/tile/wave; vmcnt(6)
// at iter top == own tile(it) loads complete; barrier => all waves'. No ds_writes pending
// so no lgkmcnt at barrier. sched_barrier(0) pins {waitcnt->barrier->STAGE} order (rule #18).
// LDS 72 KB -> still 2 independent blocks/CU, 2 waves/SIMD.
// K_swz: [ntile32][ch16][row32][8] 8KB; V_swz: [cblk][ntile32][ch4][c256][8] 16KB.
__global__ __launch_bounds__(256, 2) void attn_pv(
    const unsigned short* __restrict__ qb, const unsigned short* __restrict__ ksw,
    const unsigned short* __restrict__ vsw,
    unsigned short* __restrict__ Oa, unsigned short* __restrict__ Ob,
    float* __restrict__ la, float* __restrict__ lb)
{
    __shared__ short Ks[3][16][32][8];  // 24 KB (K triple buffer, 8 KB slots)
    __shared__ short Vs[3][4][256][8];  // 48 KB (V triple buffer, 16 KB slots)

    const int tid = threadIdx.x, wave = tid >> 6, lane = tid & 63;
    const int l31 = lane & 31, h = lane >> 5;
    const int m0 = blockIdx.x * 128, cblk = blockIdx.y;
    const int mw = m0 + wave * 32;
    const int nt0 = blockIdx.z * 128; // in 32-n tiles; 128 iters
    unsigned short* Op = blockIdx.z ? Ob : Oa;
    float* ls = blockIdx.z ? lb : la;
    const float cexp = (float)(0.08838834764831845 * 1.4426950408889634); // scale*log2e

    // Q fragments: B-operand of 32x32x16 (col=q=lane&31, k=d=(lane>>5)*8+e), 8 k-steps
    short8 qf[8];
#pragma unroll
    for (int kk = 0; kk < 8; kk++)
        qf[kk] = *(const short8*)&qb[(mw + l31) * HDIM + kk * 16 + h * 8];

    floatx16 acc[8] = {};
    float ls0 = 0.f, ls1 = 0.f, ls2 = 0.f, ls3 = 0.f;

    // staging: every wave-load = 64 lanes x 16 B = 1 KB contiguous
    // K per tile = 8 chunks of 512 shorts -> 2 chunks per wave
    // V per tile = 16 chunks -> 4 chunks per wave
    const unsigned short* kg[2];
#pragma unroll
    for (int t = 0; t < 2; t++) kg[t] = ksw + (wave * 2 + t) * 512 + lane * 8;
    const unsigned short* vg[4];
#pragma unroll
    for (int t = 0; t < 4; t++)
        vg[t] = vsw + (long)cblk * 2097152 + (wave * 4 + t) * 512 + lane * 8;

    // rotating slot pointers: (kr,vr)=tile(it), (kn,vn)=tile(it+1), (kw,vw)=stage dest it+2
    short* kr = &Ks[0][0][0][0];
    short* kn = &Ks[1][0][0][0];
    short* kw = &Ks[2][0][0][0];
    short* vr = &Vs[0][0][0][0];
    short* vn = &Vs[1][0][0][0];
    short* vw = &Vs[2][0][0][0];

#define STAGE(NT, KD, VD)                                               \
    {                                                                   \
        long nt_ = (NT);                                                \
        async16(kg[0] + nt_ * 4096, (KD) + (wave * 2 + 0) * 512);       \
        async16(kg[1] + nt_ * 4096, (KD) + (wave * 2 + 1) * 512);       \
        async16(vg[0] + nt_ * 8192, (VD) + (wave * 4 + 0) * 512);       \
        async16(vg[1] + nt_ * 8192, (VD) + (wave * 4 + 1) * 512);       \
        async16(vg[2] + nt_ * 8192, (VD) + (wave * 4 + 2) * 512);       \
        async16(vg[3] + nt_ * 8192, (VD) + (wave * 4 + 3) * 512);       \
    }

    // prologue: stage tiles 0 and 1 (12 loads in flight)
    STAGE(nt0, kr, vr);
    STAGE(nt0 + 1, kn, vn);

    for (int it = 0; it < 128; ++it) {
        // own tile(it) loads complete (6 newest may remain in flight); never drain to 0
        if (it == 127) asm volatile("s_waitcnt vmcnt(0)" ::: "memory");
        else           asm volatile("s_waitcnt vmcnt(6)" ::: "memory");
        __builtin_amdgcn_sched_barrier(0);
        __builtin_amdgcn_s_barrier(); // all waves' tile(it) staged; compute(it-1) done
        __builtin_amdgcn_sched_barrier(0);
        if (it + 2 < 128) STAGE(nt0 + it + 2, kw, vw);
        __builtin_amdgcn_sched_barrier(0);

        // ---- QK^T: S^T[32n x 32q] = K-tile @ Q^T (A=K: row=n=lane&31, k=d) ----
        floatx16 st = {};
        __builtin_amdgcn_s_setprio(1);
#pragma unroll
        for (int kk = 0; kk < 8; kk++) {
            short8 kf = *(short8*)(kr + (kk * 2 + h) * 256 + l31 * 8);
            st = __builtin_amdgcn_mfma_f32_32x32x16_bf16(kf, qf[kk], st, 0, 0, 0);
        }
        __builtin_amdgcn_s_setprio(0);

        // ---- P = exp2(st*c): lane holds P[q=l31][16 n-values]; pack consecutive-n
        // pairs (regs 2i,2i+1) to bf16x2 dwords; 4-way partial lsum (no serial chain) ----
        unsigned pk0, pk1, pk2, pk3, pk4, pk5, pk6, pk7;
        {
            float p0, p1;
#define PK(I, DST, LS) \
            p0 = __builtin_amdgcn_exp2f(st[2 * I] * cexp); \
            p1 = __builtin_amdgcn_exp2f(st[2 * I + 1] * cexp); \
            LS += p0 + p1; \
            asm("v_cvt_pk_bf16_f32 %0, %1, %2" : "=v"(DST) : "v"(p0), "v"(p1));
            PK(0, pk0, ls0) PK(1, pk1, ls1) PK(2, pk2, ls2) PK(3, pk3, ls3)
            PK(4, pk4, ls0) PK(5, pk5, ls1) PK(6, pk6, ls2) PK(7, pk7, ls3)
#undef PK
        }
        // permlane32_swap -> (pk0..pk3) = A-frag k-step0 dwords, (pk4..pk7) = k-step1
        asm("v_permlane32_swap_b32 %0, %1" : "+v"(pk0), "+v"(pk2));
        asm("v_permlane32_swap_b32 %0, %1" : "+v"(pk1), "+v"(pk3));
        asm("v_permlane32_swap_b32 %0, %1" : "+v"(pk4), "+v"(pk6));
        asm("v_permlane32_swap_b32 %0, %1" : "+v"(pk5), "+v"(pk7));
        union { unsigned u[4]; short8 s; } up0, up1;
        up0.u[0] = pk0; up0.u[1] = pk1; up0.u[2] = pk2; up0.u[3] = pk3;
        up1.u[0] = pk4; up1.u[1] = pk5; up1.u[2] = pk6; up1.u[3] = pk7;
        const short8 pa0 = up0.s, pa1 = up1.s;

        // ---- PV: O[32q x 256c] += P[32 x 32] @ V[32 x 256] (B=V: col=c=lane&31, k=n) ----
        __builtin_amdgcn_s_setprio(1);
#pragma unroll
        for (int ct = 0; ct < 8; ct++) {
            short8 bv0 = *(short8*)(vr + h * 2048 + (ct * 32 + l31) * 8);
            short8 bv1 = *(short8*)(vr + (2 + h) * 2048 + (ct * 32 + l31) * 8);
            acc[ct] = __builtin_amdgcn_mfma_f32_32x32x16_bf16(pa0, bv0, acc[ct], 0, 0, 0);
            acc[ct] = __builtin_amdgcn_mfma_f32_32x32x16_bf16(pa1, bv1, acc[ct], 0, 0, 0);
        }
        __builtin_amdgcn_s_setprio(0);

        // rotate slots: read(it+1) <- kn, stage dest <- old kr (freed after this iter's barrier)
        short* t0 = kr; kr = kn; kn = kw; kw = t0;
        short* t1 = vr; vr = vn; vn = vw; vw = t1;
    }
#undef STAGE

    // unnormalized partial O: q = (r&3)+8*(r>>2)+4*h, c = cblk*256 + ct*32 + l31
#pragma unroll
    for (int ct = 0; ct < 8; ct++) {
        int c = cblk * 256 + ct * 32 + l31;
#pragma unroll
        for (int r = 0; r < 16; r++) {
            int q = (r & 3) + 8 * (r >> 2) + 4 * h;
            Op[(long)(mw + q) * CDIM + c] = f2bf(acc[ct][r]);
        }
    }
    // partial row sums: lane q=l31 holds 16 of 32 n per tile; partner (lane^32) the rest
    if (blockIdx.y == 0) {
        float lsum = (ls0 + ls1) + (ls2 + ls3);
        lsum += __shfl_xor(lsum, 32);
        if (lane < 32) ls[mw + lane] = lsum;
    }
}

// ---------------- combine: attn = (Oa + Ob) / (la + lb), in place over Ob ----------------
__global__ __launch_bounds__(256) void combine_attn(
    const unsigned short* __restrict__ Oa, unsigned short* __restrict__ Ob,
    const float* __restrict__ la, const float* __restrict__ lb)
{
    int i = blockIdx.x * blockDim.x + threadIdx.x; // one per 8 elems
    int row = i >> 7;                              // CDIM/8 = 128
    float inv = 1.0f / (la[row] + lb[row]);
    short8 a = ((const short8*)Oa)[i];
    short8 b = ((const short8*)Ob)[i];
    short8 o;
#pragma unroll
    for (int e = 0; e < 8; e++) o[e] = (short)f2bf((bf2f(a[e]) + bf2f(b[e])) * inv);
    ((short8*)Ob)[i] = o;
}

extern "C" void kernel_launch(void* const* d_in, const int* in_sizes, int n_in,
                              void* d_out, int out_size, void* d_ws, size_t ws_size,
                              hipStream_t stream) {
    const float* x  = (const float*)d_in[0];
    const float* Wq = (const float*)d_in[1];
    const float* bq = (const float*)d_in[2];
    const float* Wk = (const float*)d_in[3];
    const float* bk = (const float*)d_in[4];
    const float* Wv = (const float*)d_in[5];
    const float* bv = (const float*)d_in[6];
    const float* Wo = (const float*)d_in[7];
    const float* bo = (const float*)d_in[8];

    char* ws = (char*)d_ws;
    unsigned short* x_bf   = (unsigned short*)(ws + 0);          // 16 MB (reused as Oa)
    unsigned short* wq_bf  = (unsigned short*)(ws + 16777216);   // 256 KB
    unsigned short* wk_bf  = (unsigned short*)(ws + 17039360);   // 256 KB
    unsigned short* wv_bf  = (unsigned short*)(ws + 17301504);   // 2 MB
    unsigned short* wo_bf  = (unsigned short*)(ws + 19398656);   // 2 MB
    unsigned short* q_bf   = (unsigned short*)(ws + 21495808);   // 2 MB
    unsigned short* k_swz  = (unsigned short*)(ws + 23592960);   // 2 MB (K swizzled)
    unsigned short* v_swz  = (unsigned short*)(ws + 25690112);   // 16 MB (V swizzled)
    unsigned short* attn_bf= (unsigned short*)(ws + 42467328);   // 16 MB (Ob, combined in place)
    float* lsum_a          = (float*)(ws + 59244544);            // 32 KB
    float* lsum_b          = (float*)(ws + 59277312);            // 32 KB

    // casts to bf16
    cast_f32_bf16<<<8192, 256, 0, stream>>>(x,  x_bf,  2097152);
    cast_f32_bf16<<<128,  256, 0, stream>>>(Wq, wq_bf, 32768);
    cast_f32_bf16<<<128,  256, 0, stream>>>(Wk, wk_bf, 32768);
    cast_f32_bf16<<<1024, 256, 0, stream>>>(Wv, wv_bf, 262144);
    cast_f32_bf16<<<1024, 256, 0, stream>>>(Wo, wo_bf, 262144);

    // projections
    gemm_nt<0><<<dim3(128, 2), 256, 0, stream>>>(x_bf, wq_bf, bq, q_bf, NTOK, HDIM, CDIM);
    gemm_nt<1><<<dim3(128, 2), 256, 0, stream>>>(x_bf, wk_bf, bk, k_swz, NTOK, HDIM, CDIM);
    gemm128_nt<2><<<dim3(64, 8), 256, 0, stream>>>(x_bf, wv_bf, bv, v_swz, NTOK, CDIM, CDIM);

    // fused attention (split-n over gridDim.z); Oa overlays dead x_bf
    attn_pv<<<dim3(64, 4, 2), 256, 0, stream>>>(q_bf, k_swz, v_swz,
                                                x_bf, attn_bf, lsum_a, lsum_b);
    combine_attn<<<4096, 256, 0, stream>>>(x_bf, attn_bf, lsum_a, lsum_b);

    // output projection (fp32 out)
    gemm128_nt<0><<<dim3(64, 8), 256, 0, stream>>>(attn_bf, wo_bf, bo, d_out, NTOK, CDIM, CDIM);
}

// Round 9
// 373.273 us; speedup vs baseline: 1.3788x; 1.0612x over previous
//
#include <hip/hip_runtime.h>

#define NTOK 8192
#define CDIM 1024
#define HDIM 128

typedef __attribute__((ext_vector_type(8))) short short8;
typedef __attribute__((ext_vector_type(4))) float floatx4;
typedef __attribute__((ext_vector_type(16))) float floatx16;

__device__ inline unsigned short f2bf(float f) {
    union { float f; unsigned u; } v; v.f = f;
    unsigned r = v.u + 0x7fffu + ((v.u >> 16) & 1u);
    return (unsigned short)(r >> 16);
}
__device__ inline float bf2f(short s) {
    union { unsigned u; float f; } v;
    v.u = ((unsigned)(unsigned short)s) << 16;
    return v.f;
}
__device__ inline void async16(const unsigned short* g, short* l) {
    __builtin_amdgcn_global_load_lds(
        (const __attribute__((address_space(1))) unsigned*)g,
        (__attribute__((address_space(3))) unsigned*)l, 16, 0, 0);
}

// ---------------- cast fp32 -> bf16, 4 elems/thread ----------------
__global__ void cast_f32_bf16(const float* __restrict__ in,
                              unsigned short* __restrict__ out, int n4) {
    int i = blockIdx.x * blockDim.x + threadIdx.x;
    if (i < n4) {
        float4 v = ((const float4*)in)[i];
        ushort4 o;
        o.x = f2bf(v.x); o.y = f2bf(v.y); o.z = f2bf(v.z); o.w = f2bf(v.w);
        ((ushort4*)out)[i] = o;
    }
}

// ---------------- fused q+k projection GEMM (64-tiles, one launch) ----------------
// grid (128, 4): y<2 -> q cols (row-major out), y>=2 -> k cols (K-swizzled out).
// Previously two serial 256-block launches at 1 block/CU each; fused = 512 blocks, 2/CU.
__global__ __launch_bounds__(256) void gemm_qk(
    const unsigned short* __restrict__ A,
    const unsigned short* __restrict__ Wq, const float* __restrict__ bq,
    const unsigned short* __restrict__ Wk, const float* __restrict__ bk,
    unsigned short* __restrict__ qout, unsigned short* __restrict__ kout, int K)
{
    __shared__ short As[4][64][8];
    __shared__ short Ws[4][64][8];
    const int tid = threadIdx.x;
    const int wave = tid >> 6, lane = tid & 63;
    const int lr = lane & 15, lc = lane >> 4;
    const int m0 = blockIdx.x * 64;
    const int isK = blockIdx.y >> 1;
    const int n0 = (blockIdx.y & 1) * 64;
    const unsigned short* W = isK ? Wk : Wq;
    const float* bias = isK ? bk : bq;

    floatx4 acc[4] = {};
    const int srow = tid >> 2, sch = tid & 3;
    const unsigned short* Ag = A + (long)(m0 + srow) * K + sch * 8;
    const unsigned short* Wg = W + (long)(n0 + srow) * K + sch * 8;

    for (int k0 = 0; k0 < K; k0 += 32) {
        *(short8*)&As[sch][srow][0] = *(const short8*)(Ag + k0);
        *(short8*)&Ws[sch][srow][0] = *(const short8*)(Wg + k0);
        __syncthreads();
        short8 a = *(short8*)&As[lc][wave * 16 + lr][0];
#pragma unroll
        for (int s = 0; s < 4; s++) {
            short8 b = *(short8*)&Ws[lc][s * 16 + lr][0];
            acc[s] = __builtin_amdgcn_mfma_f32_16x16x32_bf16(a, b, acc[s], 0, 0, 0);
        }
        __syncthreads();
    }

#pragma unroll
    for (int s = 0; s < 4; s++) {
        int h = n0 + s * 16 + lr;
        float bv = bias[h];
        int tok0 = m0 + wave * 16 + lc * 4;
#pragma unroll
        for (int r = 0; r < 4; r++) {
            int tok = tok0 + r;
            if (isK)
                kout[(tok >> 5) * 4096 + (h >> 3) * 256 + (tok & 31) * 8 + (h & 7)] =
                    f2bf(acc[s][r] + bv);
            else
                qout[(long)tok * HDIM + h] = f2bf(acc[s][r] + bv);
        }
    }
}

// ---------------- 128-tile NT GEMM, global_load_lds staging ----------------
// MODE 0: f32 out row-major; MODE 2: V-swizzled bf16 out
template<int MODE>
__global__ __launch_bounds__(256) void gemm128_nt(
    const unsigned short* __restrict__ A, const unsigned short* __restrict__ W,
    const float* __restrict__ bias, void* __restrict__ out, int M, int N, int K)
{
    __shared__ short As[128][4][8]; // [row][k-chunk][8]
    __shared__ short Ws[128][4][8];
    const int tid = threadIdx.x, wave = tid >> 6, lane = tid & 63;
    const int lr = lane & 15, lc = lane >> 4;
    const int wm = (wave >> 1) * 64, wn = (wave & 1) * 64;
    const int m0 = blockIdx.x * 128, n0 = blockIdx.y * 128;

    floatx4 acc[4][4] = {};

    const int srow = lane >> 2, sch = lane & 3;
    const unsigned short* Ag0 = A + (long)(m0 + wave * 32 + srow) * K + sch * 8;
    const unsigned short* Ag1 = Ag0 + (long)16 * K;
    const unsigned short* Wg0 = W + (long)(n0 + wave * 32 + srow) * K + sch * 8;
    const unsigned short* Wg1 = Wg0 + (long)16 * K;
    short* lA0 = &As[wave * 32][0][0];
    short* lA1 = &As[wave * 32 + 16][0][0];
    short* lW0 = &Ws[wave * 32][0][0];
    short* lW1 = &Ws[wave * 32 + 16][0][0];

    for (int k0 = 0; k0 < K; k0 += 32) {
        async16(Ag0 + k0, lA0);
        async16(Ag1 + k0, lA1);
        async16(Wg0 + k0, lW0);
        async16(Wg1 + k0, lW1);
        __syncthreads();
        short8 af[4], bfg[4];
#pragma unroll
        for (int i = 0; i < 4; i++) af[i]  = *(short8*)&As[wm + i * 16 + lr][lc][0];
#pragma unroll
        for (int j = 0; j < 4; j++) bfg[j] = *(short8*)&Ws[wn + j * 16 + lr][lc][0];
#pragma unroll
        for (int i = 0; i < 4; i++)
#pragma unroll
            for (int j = 0; j < 4; j++)
                acc[i][j] = __builtin_amdgcn_mfma_f32_16x16x32_bf16(af[i], bfg[j], acc[i][j], 0, 0, 0);
        __syncthreads();
    }

#pragma unroll
    for (int i = 0; i < 4; i++) {
        int t0 = m0 + wm + i * 16 + lc * 4;
#pragma unroll
        for (int j = 0; j < 4; j++) {
            int c = n0 + wn + j * 16 + lr;
            float bv = bias[c];
            if (MODE == 0) {
                float* o = (float*)out;
#pragma unroll
                for (int r = 0; r < 4; r++) o[(long)(t0 + r) * N + c] = acc[i][j][r] + bv;
            } else {
                unsigned short* o = (unsigned short*)out;
                ushort4 pk;
                pk.x = f2bf(acc[i][j][0] + bv); pk.y = f2bf(acc[i][j][1] + bv);
                pk.z = f2bf(acc[i][j][2] + bv); pk.w = f2bf(acc[i][j][3] + bv);
                long off = (long)(c >> 8) * 2097152 + (t0 >> 5) * 8192 +
                           ((t0 & 31) >> 3) * 2048 + (c & 255) * 8 + (t0 & 7);
                *(ushort4*)&o[off] = pk;
            }
        }
    }
}

// ---------------- fused attention: partial O = exp(QK^T*scale) @ V + rowsum ----------------
// ROUND 9: AITER-shaped schedule on the round-8 core. 8-wave block (256 q-rows),
// grid (32,4,2)=256 = 1 block/CU. Phase = 64 n (2x 32-n tiles), 64 phases -> half the
// barriers, ~3000-cyc scheduler window with two independent QK->exp->PV chains.
// Triple-buffered phase slots: K 3x16KB + V 3x32KB = 144 KB LDS. Counted vmcnt:
// top of phase p has 6 outstanding (stage(p)); issue stage(p+1) -> 12; vmcnt(6)
// drains exactly stage(p); barrier. WAR: stage(p+1) writes slot (p+1)%3, last read
// phase p-2, fenced by the p-1 barrier. Per-tile compute identical to round 8
// (32x32x16 MFMA, in-reg P via cvt_pk+permlane32_swap, 0 bank conflicts).
// K_swz: [ntile32][ch16][row32][8] 8KB; V_swz: [cblk][ntile32][ch4][c256][8] 16KB.
__global__ __launch_bounds__(512, 2) void attn_pv(
    const unsigned short* __restrict__ qb, const unsigned short* __restrict__ ksw,
    const unsigned short* __restrict__ vsw,
    unsigned short* __restrict__ Oa, unsigned short* __restrict__ Ob,
    float* __restrict__ la, float* __restrict__ lb)
{
    __shared__ short Ks[3][8192];   // 48 KB: 3 phase-slots x (2 tiles x 8 KB)
    __shared__ short Vs[3][16384];  // 96 KB: 3 phase-slots x (2 tiles x 16 KB)

    const int tid = threadIdx.x, wave = tid >> 6, lane = tid & 63;
    const int l31 = lane & 31, h = lane >> 5;
    const int m0 = blockIdx.x * 256, cblk = blockIdx.y;
    const int mw = m0 + wave * 32;
    const int nt0 = blockIdx.z * 128; // in 32-n tiles; 64 phases x 2 tiles
    unsigned short* Op = blockIdx.z ? Ob : Oa;
    float* ls = blockIdx.z ? lb : la;
    const float cexp = (float)(0.08838834764831845 * 1.4426950408889634); // scale*log2e

    // Q fragments: B-operand of 32x32x16 (col=q=lane&31, k=d=(lane>>5)*8+e), 8 k-steps
    short8 qf[8];
#pragma unroll
    for (int kk = 0; kk < 8; kk++)
        qf[kk] = *(const short8*)&qb[(mw + l31) * HDIM + kk * 16 + h * 8];

    floatx16 acc[8] = {};
    float ls0 = 0.f, ls1 = 0.f, ls2 = 0.f, ls3 = 0.f;

    // staging: each wave-load = 64 lanes x 16 B = 1 KB contiguous.
    // Per phase (2 tiles): K 16 KB = 16 chunks -> 2/wave; V 32 KB = 32 chunks -> 4/wave.
    const unsigned short* kg0 = ksw + (wave * 2 + 0) * 512 + lane * 8;
    const unsigned short* kg1 = ksw + (wave * 2 + 1) * 512 + lane * 8;
    const unsigned short* vgb = vsw + (long)cblk * 2097152 + lane * 8;
    const unsigned short* vg0 = vgb + (wave * 4 + 0) * 512;
    const unsigned short* vg1 = vgb + (wave * 4 + 1) * 512;
    const unsigned short* vg2 = vgb + (wave * 4 + 2) * 512;
    const unsigned short* vg3 = vgb + (wave * 4 + 3) * 512;

    // rotating phase slots: kr/vr = read(phase p), kw/vw = stage dest(p+1), k2/v2 = third
    short* kr = &Ks[0][0];
    short* kw = &Ks[1][0];
    short* k2 = &Ks[2][0];
    short* vr = &Vs[0][0];
    short* vw = &Vs[1][0];
    short* v2 = &Vs[2][0];

#define STAGE(P, KD, VD)                                                \
    {                                                                   \
        long ok_ = (long)(nt0 + 2 * (P)) * 4096;                        \
        long ov_ = (long)(nt0 + 2 * (P)) * 8192;                        \
        async16(kg0 + ok_, (KD) + (wave * 2 + 0) * 512);                \
        async16(kg1 + ok_, (KD) + (wave * 2 + 1) * 512);                \
        async16(vg0 + ov_, (VD) + (wave * 4 + 0) * 512);                \
        async16(vg1 + ov_, (VD) + (wave * 4 + 1) * 512);                \
        async16(vg2 + ov_, (VD) + (wave * 4 + 2) * 512);                \
        async16(vg3 + ov_, (VD) + (wave * 4 + 3) * 512);                \
    }

    // prologue: stage phase 0 (6 loads in flight)
    STAGE(0, kr, vr);

    for (int p = 0; p < 64; ++p) {
        if (p + 1 < 64) STAGE(p + 1, kw, vw);   // into slot untouched since phase p-2
        __builtin_amdgcn_sched_barrier(0);
        // drain stage(p) (oldest 6); keep stage(p+1) (newest 6) in flight
        if (p == 63) asm volatile("s_waitcnt vmcnt(0)" ::: "memory");
        else         asm volatile("s_waitcnt vmcnt(6)" ::: "memory");
        __builtin_amdgcn_sched_barrier(0);
        __builtin_amdgcn_s_barrier(); // all waves staged phase p & finished phase p-1
        __builtin_amdgcn_sched_barrier(0);

#pragma unroll
        for (int t = 0; t < 2; t++) {
            short* kb = kr + t * 4096;
            short* vb = vr + t * 8192;

            // ---- QK^T: S^T[32n x 32q] = K-tile @ Q^T (A=K: row=n=lane&31, k=d) ----
            floatx16 st = {};
            __builtin_amdgcn_s_setprio(1);
#pragma unroll
            for (int kk = 0; kk < 8; kk++) {
                short8 kf = *(short8*)(kb + (kk * 2 + h) * 256 + l31 * 8);
                st = __builtin_amdgcn_mfma_f32_32x32x16_bf16(kf, qf[kk], st, 0, 0, 0);
            }
            __builtin_amdgcn_s_setprio(0);

            // ---- P = exp2(st*c): pack consecutive-n pairs to bf16x2; 4-way lsum ----
            unsigned pk0, pk1, pk2, pk3, pk4, pk5, pk6, pk7;
            {
                float p0, p1;
#define PK(I, DST, LS) \
                p0 = __builtin_amdgcn_exp2f(st[2 * I] * cexp); \
                p1 = __builtin_amdgcn_exp2f(st[2 * I + 1] * cexp); \
                LS += p0 + p1; \
                asm("v_cvt_pk_bf16_f32 %0, %1, %2" : "=v"(DST) : "v"(p0), "v"(p1));
                PK(0, pk0, ls0) PK(1, pk1, ls1) PK(2, pk2, ls2) PK(3, pk3, ls3)
                PK(4, pk4, ls0) PK(5, pk5, ls1) PK(6, pk6, ls2) PK(7, pk7, ls3)
#undef PK
            }
            // permlane32_swap -> (pk0..pk3) = A-frag k-step0, (pk4..pk7) = k-step1
            asm("v_permlane32_swap_b32 %0, %1" : "+v"(pk0), "+v"(pk2));
            asm("v_permlane32_swap_b32 %0, %1" : "+v"(pk1), "+v"(pk3));
            asm("v_permlane32_swap_b32 %0, %1" : "+v"(pk4), "+v"(pk6));
            asm("v_permlane32_swap_b32 %0, %1" : "+v"(pk5), "+v"(pk7));
            union { unsigned u[4]; short8 s; } up0, up1;
            up0.u[0] = pk0; up0.u[1] = pk1; up0.u[2] = pk2; up0.u[3] = pk3;
            up1.u[0] = pk4; up1.u[1] = pk5; up1.u[2] = pk6; up1.u[3] = pk7;
            const short8 pa0 = up0.s, pa1 = up1.s;

            // ---- PV: O[32q x 256c] += P[32x32] @ V[32x256] (B=V: col=c=lane&31, k=n) ----
            __builtin_amdgcn_s_setprio(1);
#pragma unroll
            for (int ct = 0; ct < 8; ct++) {
                short8 bv0 = *(short8*)(vb + h * 2048 + (ct * 32 + l31) * 8);
                short8 bv1 = *(short8*)(vb + (2 + h) * 2048 + (ct * 32 + l31) * 8);
                acc[ct] = __builtin_amdgcn_mfma_f32_32x32x16_bf16(pa0, bv0, acc[ct], 0, 0, 0);
                acc[ct] = __builtin_amdgcn_mfma_f32_32x32x16_bf16(pa1, bv1, acc[ct], 0, 0, 0);
            }
            __builtin_amdgcn_s_setprio(0);
        }

        // rotate slots: read <- staged(p+1); stage dest <- third; third <- old read
        short* t0 = kr; kr = kw; kw = k2; k2 = t0;
        short* t1 = vr; vr = vw; vw = v2; v2 = t1;
    }
#undef STAGE

    // unnormalized partial O: q = (r&3)+8*(r>>2)+4*h, c = cblk*256 + ct*32 + l31
#pragma unroll
    for (int ct = 0; ct < 8; ct++) {
        int c = cblk * 256 + ct * 32 + l31;
#pragma unroll
        for (int r = 0; r < 16; r++) {
            int q = (r & 3) + 8 * (r >> 2) + 4 * h;
            Op[(long)(mw + q) * CDIM + c] = f2bf(acc[ct][r]);
        }
    }
    // partial row sums: lane q=l31 holds 16 of 32 n per tile; partner (lane^32) the rest
    if (blockIdx.y == 0) {
        float lsum = (ls0 + ls1) + (ls2 + ls3);
        lsum += __shfl_xor(lsum, 32);
        if (lane < 32) ls[mw + lane] = lsum;
    }
}

// ---------------- combine: attn = (Oa + Ob) / (la + lb), in place over Ob ----------------
__global__ __launch_bounds__(256) void combine_attn(
    const unsigned short* __restrict__ Oa, unsigned short* __restrict__ Ob,
    const float* __restrict__ la, const float* __restrict__ lb)
{
    int i = blockIdx.x * blockDim.x + threadIdx.x; // one per 8 elems
    int row = i >> 7;                              // CDIM/8 = 128
    float inv = 1.0f / (la[row] + lb[row]);
    short8 a = ((const short8*)Oa)[i];
    short8 b = ((const short8*)Ob)[i];
    short8 o;
#pragma unroll
    for (int e = 0; e < 8; e++) o[e] = (short)f2bf((bf2f(a[e]) + bf2f(b[e])) * inv);
    ((short8*)Ob)[i] = o;
}

extern "C" void kernel_launch(void* const* d_in, const int* in_sizes, int n_in,
                              void* d_out, int out_size, void* d_ws, size_t ws_size,
                              hipStream_t stream) {
    const float* x  = (const float*)d_in[0];
    const float* Wq = (const float*)d_in[1];
    const float* bq = (const float*)d_in[2];
    const float* Wk = (const float*)d_in[3];
    const float* bk = (const float*)d_in[4];
    const float* Wv = (const float*)d_in[5];
    const float* bv = (const float*)d_in[6];
    const float* Wo = (const float*)d_in[7];
    const float* bo = (const float*)d_in[8];

    char* ws = (char*)d_ws;
    unsigned short* x_bf   = (unsigned short*)(ws + 0);          // 16 MB (reused as Oa)
    unsigned short* wq_bf  = (unsigned short*)(ws + 16777216);   // 256 KB
    unsigned short* wk_bf  = (unsigned short*)(ws + 17039360);   // 256 KB
    unsigned short* wv_bf  = (unsigned short*)(ws + 17301504);   // 2 MB
    unsigned short* wo_bf  = (unsigned short*)(ws + 19398656);   // 2 MB
    unsigned short* q_bf   = (unsigned short*)(ws + 21495808);   // 2 MB
    unsigned short* k_swz  = (unsigned short*)(ws + 23592960);   // 2 MB (K swizzled)
    unsigned short* v_swz  = (unsigned short*)(ws + 25690112);   // 16 MB (V swizzled)
    unsigned short* attn_bf= (unsigned short*)(ws + 42467328);   // 16 MB (Ob, combined in place)
    float* lsum_a          = (float*)(ws + 59244544);            // 32 KB
    float* lsum_b          = (float*)(ws + 59277312);            // 32 KB

    // casts to bf16
    cast_f32_bf16<<<8192, 256, 0, stream>>>(x,  x_bf,  2097152);
    cast_f32_bf16<<<128,  256, 0, stream>>>(Wq, wq_bf, 32768);
    cast_f32_bf16<<<128,  256, 0, stream>>>(Wk, wk_bf, 32768);
    cast_f32_bf16<<<1024, 256, 0, stream>>>(Wv, wv_bf, 262144);
    cast_f32_bf16<<<1024, 256, 0, stream>>>(Wo, wo_bf, 262144);

    // projections (q+k fused into one launch; v as before)
    gemm_qk<<<dim3(128, 4), 256, 0, stream>>>(x_bf, wq_bf, bq, wk_bf, bk,
                                              q_bf, k_swz, CDIM);
    gemm128_nt<2><<<dim3(64, 8), 256, 0, stream>>>(x_bf, wv_bf, bv, v_swz, NTOK, CDIM, CDIM);

    // fused attention (split-n over gridDim.z); Oa overlays dead x_bf
    attn_pv<<<dim3(32, 4, 2), 512, 0, stream>>>(q_bf, k_swz, v_swz,
                                                x_bf, attn_bf, lsum_a, lsum_b);
    combine_attn<<<4096, 256, 0, stream>>>(x_bf, attn_bf, lsum_a, lsum_b);

    // output projection (fp32 out)
    gemm128_nt<0><<<dim3(64, 8), 256, 0, stream>>>(attn_bf, wo_bf, bo, d_out, NTOK, CDIM, CDIM);
}

// Round 10
// 358.779 us; speedup vs baseline: 1.4345x; 1.0404x over previous
//
#include <hip/hip_runtime.h>

#define NTOK 8192
#define CDIM 1024
#define HDIM 128

typedef __attribute__((ext_vector_type(8))) short short8;
typedef __attribute__((ext_vector_type(4))) float floatx4;
typedef __attribute__((ext_vector_type(16))) float floatx16;

__device__ inline unsigned short f2bf(float f) {
    union { float f; unsigned u; } v; v.f = f;
    unsigned r = v.u + 0x7fffu + ((v.u >> 16) & 1u);
    return (unsigned short)(r >> 16);
}
__device__ inline float bf2f(short s) {
    union { unsigned u; float f; } v;
    v.u = ((unsigned)(unsigned short)s) << 16;
    return v.f;
}
__device__ inline void async16(const unsigned short* g, short* l) {
    __builtin_amdgcn_global_load_lds(
        (const __attribute__((address_space(1))) unsigned*)g,
        (__attribute__((address_space(3))) unsigned*)l, 16, 0, 0);
}

// ---------------- fused cast fp32 -> bf16 for all 5 inputs (one launch) ----------------
// block ranges: [0,8192) x | [8192,9216) Wv | [9216,10240) Wo | [10240,10368) Wq | rest Wk
__global__ __launch_bounds__(256) void cast_all(
    const float* __restrict__ x,  const float* __restrict__ Wv,
    const float* __restrict__ Wo, const float* __restrict__ Wq,
    const float* __restrict__ Wk,
    unsigned short* __restrict__ xo, unsigned short* __restrict__ wvo,
    unsigned short* __restrict__ woo, unsigned short* __restrict__ wqo,
    unsigned short* __restrict__ wko)
{
    int b = blockIdx.x;
    const float* in; unsigned short* out; int base;
    if (b < 8192)       { in = x;  out = xo;  base = b; }
    else if (b < 9216)  { in = Wv; out = wvo; base = b - 8192; }
    else if (b < 10240) { in = Wo; out = woo; base = b - 9216; }
    else if (b < 10368) { in = Wq; out = wqo; base = b - 10240; }
    else                { in = Wk; out = wko; base = b - 10368; }
    int i = base * 256 + threadIdx.x;
    float4 v = ((const float4*)in)[i];
    ushort4 o;
    o.x = f2bf(v.x); o.y = f2bf(v.y); o.z = f2bf(v.z); o.w = f2bf(v.w);
    ((ushort4*)out)[i] = o;
}

// ---------------- fused q+k projection GEMM (64-tiles, one launch) ----------------
// grid (128, 4): y<2 -> q cols (row-major out), y>=2 -> k cols (K-swizzled out).
__global__ __launch_bounds__(256) void gemm_qk(
    const unsigned short* __restrict__ A,
    const unsigned short* __restrict__ Wq, const float* __restrict__ bq,
    const unsigned short* __restrict__ Wk, const float* __restrict__ bk,
    unsigned short* __restrict__ qout, unsigned short* __restrict__ kout, int K)
{
    __shared__ short As[4][64][8];
    __shared__ short Ws[4][64][8];
    const int tid = threadIdx.x;
    const int wave = tid >> 6, lane = tid & 63;
    const int lr = lane & 15, lc = lane >> 4;
    const int m0 = blockIdx.x * 64;
    const int isK = blockIdx.y >> 1;
    const int n0 = (blockIdx.y & 1) * 64;
    const unsigned short* W = isK ? Wk : Wq;
    const float* bias = isK ? bk : bq;

    floatx4 acc[4] = {};
    const int srow = tid >> 2, sch = tid & 3;
    const unsigned short* Ag = A + (long)(m0 + srow) * K + sch * 8;
    const unsigned short* Wg = W + (long)(n0 + srow) * K + sch * 8;

    for (int k0 = 0; k0 < K; k0 += 32) {
        *(short8*)&As[sch][srow][0] = *(const short8*)(Ag + k0);
        *(short8*)&Ws[sch][srow][0] = *(const short8*)(Wg + k0);
        __syncthreads();
        short8 a = *(short8*)&As[lc][wave * 16 + lr][0];
#pragma unroll
        for (int s = 0; s < 4; s++) {
            short8 b = *(short8*)&Ws[lc][s * 16 + lr][0];
            acc[s] = __builtin_amdgcn_mfma_f32_16x16x32_bf16(a, b, acc[s], 0, 0, 0);
        }
        __syncthreads();
    }

#pragma unroll
    for (int s = 0; s < 4; s++) {
        int h = n0 + s * 16 + lr;
        float bv = bias[h];
        int tok0 = m0 + wave * 16 + lc * 4;
#pragma unroll
        for (int r = 0; r < 4; r++) {
            int tok = tok0 + r;
            if (isK)
                kout[(tok >> 5) * 4096 + (h >> 3) * 256 + (tok & 31) * 8 + (h & 7)] =
                    f2bf(acc[s][r] + bv);
            else
                qout[(long)tok * HDIM + h] = f2bf(acc[s][r] + bv);
        }
    }
}

// ---------------- 128-tile NT GEMM, aged-drain double-buffer ----------------
// MODE 0: f32 out row-major; MODE 2: V-swizzled bf16 out
// ROUND 10: stage(k+1) issued right AFTER the step-k barrier -> by the time the step-k+1
// __syncthreads drains vmcnt, loads have aged one full compute step. ONE barrier per
// K-step (was two + un-aged drain). Double-buffered slots: stage(k+1) writes the slot
// read at step k-1, fenced by this step's barrier.
template<int MODE>
__global__ __launch_bounds__(256) void gemm128_nt(
    const unsigned short* __restrict__ A, const unsigned short* __restrict__ W,
    const float* __restrict__ bias, void* __restrict__ out, int M, int N, int K)
{
    __shared__ short As[2][128][4][8]; // 2 x 8 KB
    __shared__ short Ws[2][128][4][8];
    const int tid = threadIdx.x, wave = tid >> 6, lane = tid & 63;
    const int lr = lane & 15, lc = lane >> 4;
    const int wm = (wave >> 1) * 64, wn = (wave & 1) * 64;
    const int m0 = blockIdx.x * 128, n0 = blockIdx.y * 128;

    floatx4 acc[4][4] = {};

    const int srow = lane >> 2, sch = lane & 3;
    const unsigned short* Ag0 = A + (long)(m0 + wave * 32 + srow) * K + sch * 8;
    const unsigned short* Ag1 = Ag0 + (long)16 * K;
    const unsigned short* Wg0 = W + (long)(n0 + wave * 32 + srow) * K + sch * 8;
    const unsigned short* Wg1 = Wg0 + (long)16 * K;

#define GSTAGE(K0, S)                                        \
    {                                                        \
        async16(Ag0 + (K0), &As[S][wave * 32][0][0]);        \
        async16(Ag1 + (K0), &As[S][wave * 32 + 16][0][0]);   \
        async16(Wg0 + (K0), &Ws[S][wave * 32][0][0]);        \
        async16(Wg1 + (K0), &Ws[S][wave * 32 + 16][0][0]);   \
    }

    GSTAGE(0, 0);
    int s = 0;
    for (int k0 = 0; k0 < K; k0 += 32, s ^= 1) {
        __syncthreads(); // drains stage(k) [aged one step, except k=0]; publishes slot s
        if (k0 + 32 < K) GSTAGE(k0 + 32, s ^ 1); // slot s^1: last read step k-1, fenced
        short8 af[4], bfg[4];
#pragma unroll
        for (int i = 0; i < 4; i++) af[i]  = *(short8*)&As[s][wm + i * 16 + lr][lc][0];
#pragma unroll
        for (int j = 0; j < 4; j++) bfg[j] = *(short8*)&Ws[s][wn + j * 16 + lr][lc][0];
#pragma unroll
        for (int i = 0; i < 4; i++)
#pragma unroll
            for (int j = 0; j < 4; j++)
                acc[i][j] = __builtin_amdgcn_mfma_f32_16x16x32_bf16(af[i], bfg[j], acc[i][j], 0, 0, 0);
    }
#undef GSTAGE

#pragma unroll
    for (int i = 0; i < 4; i++) {
        int t0 = m0 + wm + i * 16 + lc * 4;
#pragma unroll
        for (int j = 0; j < 4; j++) {
            int c = n0 + wn + j * 16 + lr;
            float bv = bias[c];
            if (MODE == 0) {
                float* o = (float*)out;
#pragma unroll
                for (int r = 0; r < 4; r++) o[(long)(t0 + r) * N + c] = acc[i][j][r] + bv;
            } else {
                unsigned short* o = (unsigned short*)out;
                ushort4 pk;
                pk.x = f2bf(acc[i][j][0] + bv); pk.y = f2bf(acc[i][j][1] + bv);
                pk.z = f2bf(acc[i][j][2] + bv); pk.w = f2bf(acc[i][j][3] + bv);
                long off = (long)(c >> 8) * 2097152 + (t0 >> 5) * 8192 +
                           ((t0 & 31) >> 3) * 2048 + (c & 255) * 8 + (t0 & 7);
                *(ushort4*)&o[off] = pk;
            }
        }
    }
}

// ---------------- fused attention: partial O = exp(QK^T*scale) @ V + rowsum ----------------
// ROUND 10: round-9 structure (8-wave block, 64 phases x 2 tiles, triple-buffered slots,
// counted vmcnt(6), in-reg P) + cross-tile MFMA batching: QK(t0) and QK(t1) interleaved
// (two independent st chains fill the MFMA pipe), then exp(t0)->PV(t0) || exp(t1)->PV(t1).
// K_swz: [ntile32][ch16][row32][8] 8KB; V_swz: [cblk][ntile32][ch4][c256][8] 16KB.
__global__ __launch_bounds__(512, 2) void attn_pv(
    const unsigned short* __restrict__ qb, const unsigned short* __restrict__ ksw,
    const unsigned short* __restrict__ vsw,
    unsigned short* __restrict__ Oa, unsigned short* __restrict__ Ob,
    float* __restrict__ la, float* __restrict__ lb)
{
    __shared__ short Ks[3][8192];   // 48 KB: 3 phase-slots x (2 tiles x 8 KB)
    __shared__ short Vs[3][16384];  // 96 KB: 3 phase-slots x (2 tiles x 16 KB)

    const int tid = threadIdx.x, wave = tid >> 6, lane = tid & 63;
    const int l31 = lane & 31, h = lane >> 5;
    const int m0 = blockIdx.x * 256, cblk = blockIdx.y;
    const int mw = m0 + wave * 32;
    const int nt0 = blockIdx.z * 128; // in 32-n tiles; 64 phases x 2 tiles
    unsigned short* Op = blockIdx.z ? Ob : Oa;
    float* ls = blockIdx.z ? lb : la;
    const float cexp = (float)(0.08838834764831845 * 1.4426950408889634); // scale*log2e

    // Q fragments: B-operand of 32x32x16 (col=q=lane&31, k=d=(lane>>5)*8+e), 8 k-steps
    short8 qf[8];
#pragma unroll
    for (int kk = 0; kk < 8; kk++)
        qf[kk] = *(const short8*)&qb[(mw + l31) * HDIM + kk * 16 + h * 8];

    floatx16 acc[8] = {};
    float ls0 = 0.f, ls1 = 0.f, ls2 = 0.f, ls3 = 0.f;

    // staging: each wave-load = 64 lanes x 16 B = 1 KB contiguous.
    const unsigned short* kg0 = ksw + (wave * 2 + 0) * 512 + lane * 8;
    const unsigned short* kg1 = ksw + (wave * 2 + 1) * 512 + lane * 8;
    const unsigned short* vgb = vsw + (long)cblk * 2097152 + lane * 8;
    const unsigned short* vg0 = vgb + (wave * 4 + 0) * 512;
    const unsigned short* vg1 = vgb + (wave * 4 + 1) * 512;
    const unsigned short* vg2 = vgb + (wave * 4 + 2) * 512;
    const unsigned short* vg3 = vgb + (wave * 4 + 3) * 512;

    short* kr = &Ks[0][0];
    short* kw = &Ks[1][0];
    short* k2 = &Ks[2][0];
    short* vr = &Vs[0][0];
    short* vw = &Vs[1][0];
    short* v2 = &Vs[2][0];

#define STAGE(P, KD, VD)                                                \
    {                                                                   \
        long ok_ = (long)(nt0 + 2 * (P)) * 4096;                        \
        long ov_ = (long)(nt0 + 2 * (P)) * 8192;                        \
        async16(kg0 + ok_, (KD) + (wave * 2 + 0) * 512);                \
        async16(kg1 + ok_, (KD) + (wave * 2 + 1) * 512);                \
        async16(vg0 + ov_, (VD) + (wave * 4 + 0) * 512);                \
        async16(vg1 + ov_, (VD) + (wave * 4 + 1) * 512);                \
        async16(vg2 + ov_, (VD) + (wave * 4 + 2) * 512);                \
        async16(vg3 + ov_, (VD) + (wave * 4 + 3) * 512);                \
    }

    STAGE(0, kr, vr);

    for (int ph = 0; ph < 64; ++ph) {
        if (ph + 1 < 64) STAGE(ph + 1, kw, vw);   // into slot untouched since ph-2
        __builtin_amdgcn_sched_barrier(0);
        if (ph == 63) asm volatile("s_waitcnt vmcnt(0)" ::: "memory");
        else          asm volatile("s_waitcnt vmcnt(6)" ::: "memory");
        __builtin_amdgcn_sched_barrier(0);
        __builtin_amdgcn_s_barrier(); // all waves staged ph & finished ph-1
        __builtin_amdgcn_sched_barrier(0);

        short* kb0 = kr;        short* vb0 = vr;
        short* kb1 = kr + 4096; short* vb1 = vr + 8192;

        // ---- QK^T both tiles, interleaved (two independent accumulator chains) ----
        floatx16 st0 = {}, st1 = {};
        __builtin_amdgcn_s_setprio(1);
#pragma unroll
        for (int kk = 0; kk < 8; kk++) {
            short8 kf0 = *(short8*)(kb0 + (kk * 2 + h) * 256 + l31 * 8);
            short8 kf1 = *(short8*)(kb1 + (kk * 2 + h) * 256 + l31 * 8);
            st0 = __builtin_amdgcn_mfma_f32_32x32x16_bf16(kf0, qf[kk], st0, 0, 0, 0);
            st1 = __builtin_amdgcn_mfma_f32_32x32x16_bf16(kf1, qf[kk], st1, 0, 0, 0);
        }
        __builtin_amdgcn_s_setprio(0);

#define EXP_PACK(ST, PA0, PA1)                                                      \
        short8 PA0, PA1;                                                            \
        {                                                                           \
            unsigned pk0, pk1, pk2, pk3, pk4, pk5, pk6, pk7;                        \
            float p0, p1;                                                           \
            _Pragma("clang diagnostic push")                                        \
            p0 = __builtin_amdgcn_exp2f(ST[0] * cexp);                              \
            p1 = __builtin_amdgcn_exp2f(ST[1] * cexp);                              \
            ls0 += p0 + p1;                                                         \
            asm("v_cvt_pk_bf16_f32 %0, %1, %2" : "=v"(pk0) : "v"(p0), "v"(p1));     \
            p0 = __builtin_amdgcn_exp2f(ST[2] * cexp);                              \
            p1 = __builtin_amdgcn_exp2f(ST[3] * cexp);                              \
            ls1 += p0 + p1;                                                         \
            asm("v_cvt_pk_bf16_f32 %0, %1, %2" : "=v"(pk1) : "v"(p0), "v"(p1));     \
            p0 = __builtin_amdgcn_exp2f(ST[4] * cexp);                              \
            p1 = __builtin_amdgcn_exp2f(ST[5] * cexp);                              \
            ls2 += p0 + p1;                                                         \
            asm("v_cvt_pk_bf16_f32 %0, %1, %2" : "=v"(pk2) : "v"(p0), "v"(p1));     \
            p0 = __builtin_amdgcn_exp2f(ST[6] * cexp);                              \
            p1 = __builtin_amdgcn_exp2f(ST[7] * cexp);                              \
            ls3 += p0 + p1;                                                         \
            asm("v_cvt_pk_bf16_f32 %0, %1, %2" : "=v"(pk3) : "v"(p0), "v"(p1));     \
            p0 = __builtin_amdgcn_exp2f(ST[8] * cexp);                              \
            p1 = __builtin_amdgcn_exp2f(ST[9] * cexp);                              \
            ls0 += p0 + p1;                                                         \
            asm("v_cvt_pk_bf16_f32 %0, %1, %2" : "=v"(pk4) : "v"(p0), "v"(p1));     \
            p0 = __builtin_amdgcn_exp2f(ST[10] * cexp);                             \
            p1 = __builtin_amdgcn_exp2f(ST[11] * cexp);                             \
            ls1 += p0 + p1;                                                         \
            asm("v_cvt_pk_bf16_f32 %0, %1, %2" : "=v"(pk5) : "v"(p0), "v"(p1));     \
            p0 = __builtin_amdgcn_exp2f(ST[12] * cexp);                             \
            p1 = __builtin_amdgcn_exp2f(ST[13] * cexp);                             \
            ls2 += p0 + p1;                                                         \
            asm("v_cvt_pk_bf16_f32 %0, %1, %2" : "=v"(pk6) : "v"(p0), "v"(p1));     \
            p0 = __builtin_amdgcn_exp2f(ST[14] * cexp);                             \
            p1 = __builtin_amdgcn_exp2f(ST[15] * cexp);                             \
            ls3 += p0 + p1;                                                         \
            asm("v_cvt_pk_bf16_f32 %0, %1, %2" : "=v"(pk7) : "v"(p0), "v"(p1));     \
            _Pragma("clang diagnostic pop")                                         \
            asm("v_permlane32_swap_b32 %0, %1" : "+v"(pk0), "+v"(pk2));             \
            asm("v_permlane32_swap_b32 %0, %1" : "+v"(pk1), "+v"(pk3));             \
            asm("v_permlane32_swap_b32 %0, %1" : "+v"(pk4), "+v"(pk6));             \
            asm("v_permlane32_swap_b32 %0, %1" : "+v"(pk5), "+v"(pk7));             \
            union { unsigned u[4]; short8 s; } up0_, up1_;                          \
            up0_.u[0] = pk0; up0_.u[1] = pk1; up0_.u[2] = pk2; up0_.u[3] = pk3;     \
            up1_.u[0] = pk4; up1_.u[1] = pk5; up1_.u[2] = pk6; up1_.u[3] = pk7;     \
            PA0 = up0_.s; PA1 = up1_.s;                                             \
        }

#define PV(VB, PA0, PA1)                                                            \
        __builtin_amdgcn_s_setprio(1);                                              \
        _Pragma("unroll")                                                           \
        for (int ct = 0; ct < 8; ct++) {                                            \
            short8 bv0 = *(short8*)((VB) + h * 2048 + (ct * 32 + l31) * 8);         \
            short8 bv1 = *(short8*)((VB) + (2 + h) * 2048 + (ct * 32 + l31) * 8);   \
            acc[ct] = __builtin_amdgcn_mfma_f32_32x32x16_bf16(PA0, bv0, acc[ct], 0, 0, 0); \
            acc[ct] = __builtin_amdgcn_mfma_f32_32x32x16_bf16(PA1, bv1, acc[ct], 0, 0, 0); \
        }                                                                           \
        __builtin_amdgcn_s_setprio(0);

        // exp(t0) -> PV(t0); exp(t1) -> PV(t1). PV(t0) is independent of exp(t1):
        // compiler can overlap the VALU tail of t1 with t0's MFMA cluster.
        EXP_PACK(st0, pa0_0, pa1_0)
        EXP_PACK(st1, pa0_1, pa1_1)
        PV(vb0, pa0_0, pa1_0)
        PV(vb1, pa0_1, pa1_1)

#undef EXP_PACK
#undef PV

        // rotate slots
        short* t0p = kr; kr = kw; kw = k2; k2 = t0p;
        short* t1p = vr; vr = vw; vw = v2; v2 = t1p;
    }
#undef STAGE

    // unnormalized partial O: q = (r&3)+8*(r>>2)+4*h, c = cblk*256 + ct*32 + l31
#pragma unroll
    for (int ct = 0; ct < 8; ct++) {
        int c = cblk * 256 + ct * 32 + l31;
#pragma unroll
        for (int r = 0; r < 16; r++) {
            int q = (r & 3) + 8 * (r >> 2) + 4 * h;
            Op[(long)(mw + q) * CDIM + c] = f2bf(acc[ct][r]);
        }
    }
    // partial row sums: lane q=l31 holds 16 of 32 n per tile; partner (lane^32) the rest
    if (blockIdx.y == 0) {
        float lsum = (ls0 + ls1) + (ls2 + ls3);
        lsum += __shfl_xor(lsum, 32);
        if (lane < 32) ls[mw + lane] = lsum;
    }
}

// ---------------- combine: attn = (Oa + Ob) / (la + lb), in place over Ob ----------------
__global__ __launch_bounds__(256) void combine_attn(
    const unsigned short* __restrict__ Oa, unsigned short* __restrict__ Ob,
    const float* __restrict__ la, const float* __restrict__ lb)
{
    int i = blockIdx.x * blockDim.x + threadIdx.x; // one per 8 elems
    int row = i >> 7;                              // CDIM/8 = 128
    float inv = 1.0f / (la[row] + lb[row]);
    short8 a = ((const short8*)Oa)[i];
    short8 b = ((const short8*)Ob)[i];
    short8 o;
#pragma unroll
    for (int e = 0; e < 8; e++) o[e] = (short)f2bf((bf2f(a[e]) + bf2f(b[e])) * inv);
    ((short8*)Ob)[i] = o;
}

extern "C" void kernel_launch(void* const* d_in, const int* in_sizes, int n_in,
                              void* d_out, int out_size, void* d_ws, size_t ws_size,
                              hipStream_t stream) {
    const float* x  = (const float*)d_in[0];
    const float* Wq = (const float*)d_in[1];
    const float* bq = (const float*)d_in[2];
    const float* Wk = (const float*)d_in[3];
    const float* bk = (const float*)d_in[4];
    const float* Wv = (const float*)d_in[5];
    const float* bv = (const float*)d_in[6];
    const float* Wo = (const float*)d_in[7];
    const float* bo = (const float*)d_in[8];

    char* ws = (char*)d_ws;
    unsigned short* x_bf   = (unsigned short*)(ws + 0);          // 16 MB (reused as Oa)
    unsigned short* wq_bf  = (unsigned short*)(ws + 16777216);   // 256 KB
    unsigned short* wk_bf  = (unsigned short*)(ws + 17039360);   // 256 KB
    unsigned short* wv_bf  = (unsigned short*)(ws + 17301504);   // 2 MB
    unsigned short* wo_bf  = (unsigned short*)(ws + 19398656);   // 2 MB
    unsigned short* q_bf   = (unsigned short*)(ws + 21495808);   // 2 MB
    unsigned short* k_swz  = (unsigned short*)(ws + 23592960);   // 2 MB (K swizzled)
    unsigned short* v_swz  = (unsigned short*)(ws + 25690112);   // 16 MB (V swizzled)
    unsigned short* attn_bf= (unsigned short*)(ws + 42467328);   // 16 MB (Ob, combined in place)
    float* lsum_a          = (float*)(ws + 59244544);            // 32 KB
    float* lsum_b          = (float*)(ws + 59277312);            // 32 KB

    // all casts in one launch
    cast_all<<<10496, 256, 0, stream>>>(x, Wv, Wo, Wq, Wk,
                                        x_bf, wv_bf, wo_bf, wq_bf, wk_bf);

    // projections (q+k fused; v)
    gemm_qk<<<dim3(128, 4), 256, 0, stream>>>(x_bf, wq_bf, bq, wk_bf, bk,
                                              q_bf, k_swz, CDIM);
    gemm128_nt<2><<<dim3(64, 8), 256, 0, stream>>>(x_bf, wv_bf, bv, v_swz, NTOK, CDIM, CDIM);

    // fused attention (split-n over gridDim.z); Oa overlays dead x_bf
    attn_pv<<<dim3(32, 4, 2), 512, 0, stream>>>(q_bf, k_swz, v_swz,
                                                x_bf, attn_bf, lsum_a, lsum_b);
    combine_attn<<<4096, 256, 0, stream>>>(x_bf, attn_bf, lsum_a, lsum_b);

    // output projection (fp32 out)
    gemm128_nt<0><<<dim3(64, 8), 256, 0, stream>>>(attn_bf, wo_bf, bo, d_out, NTOK, CDIM, CDIM);
}

// Round 11
// 343.727 us; speedup vs baseline: 1.4973x; 1.0438x over previous
//
#include <hip/hip_runtime.h>

#define NTOK 8192
#define CDIM 1024
#define HDIM 128

typedef __attribute__((ext_vector_type(8))) short short8;
typedef __attribute__((ext_vector_type(4))) float floatx4;
typedef __attribute__((ext_vector_type(16))) float floatx16;

__device__ inline unsigned short f2bf(float f) {
    union { float f; unsigned u; } v; v.f = f;
    unsigned r = v.u + 0x7fffu + ((v.u >> 16) & 1u);
    return (unsigned short)(r >> 16);
}
__device__ inline float bf2f(short s) {
    union { unsigned u; float f; } v;
    v.u = ((unsigned)(unsigned short)s) << 16;
    return v.f;
}
__device__ inline void async16(const unsigned short* g, short* l) {
    __builtin_amdgcn_global_load_lds(
        (const __attribute__((address_space(1))) unsigned*)g,
        (__attribute__((address_space(3))) unsigned*)l, 16, 0, 0);
}

// ---------------- fused cast fp32 -> bf16 for all 5 inputs (one launch) ----------------
__global__ __launch_bounds__(256) void cast_all(
    const float* __restrict__ x,  const float* __restrict__ Wv,
    const float* __restrict__ Wo, const float* __restrict__ Wq,
    const float* __restrict__ Wk,
    unsigned short* __restrict__ xo, unsigned short* __restrict__ wvo,
    unsigned short* __restrict__ woo, unsigned short* __restrict__ wqo,
    unsigned short* __restrict__ wko)
{
    int b = blockIdx.x;
    const float* in; unsigned short* out; int base;
    if (b < 8192)       { in = x;  out = xo;  base = b; }
    else if (b < 9216)  { in = Wv; out = wvo; base = b - 8192; }
    else if (b < 10240) { in = Wo; out = woo; base = b - 9216; }
    else if (b < 10368) { in = Wq; out = wqo; base = b - 10240; }
    else                { in = Wk; out = wko; base = b - 10368; }
    int i = base * 256 + threadIdx.x;
    float4 v = ((const float4*)in)[i];
    ushort4 o;
    o.x = f2bf(v.x); o.y = f2bf(v.y); o.z = f2bf(v.z); o.w = f2bf(v.w);
    ((ushort4*)out)[i] = o;
}

// ---------------- unified q/k/v projection: 128-tile NT GEMM, T3/T4 K-loop ----------------
// grid (64, 10): y=0 -> q (row-major bf16), y=1 -> k (K-swz), y>=2 -> v (V-swz, n0=(y-2)*128)
// Triple-buffered counted-vmcnt loop (attn-verified slot discipline): stage(k+1) into slot
// (k+1)%3 (distinct from read(k) and still-being-read(k-1)); vmcnt(4) keeps stage(k+1) in
// flight across the barrier; ONE barrier/K-step; loads age a full compute step.
__global__ __launch_bounds__(256, 2) void gemm_proj(
    const unsigned short* __restrict__ A,
    const unsigned short* __restrict__ Wq, const float* __restrict__ bq,
    const unsigned short* __restrict__ Wk, const float* __restrict__ bk,
    const unsigned short* __restrict__ Wv, const float* __restrict__ bv,
    unsigned short* __restrict__ qout, unsigned short* __restrict__ kout,
    unsigned short* __restrict__ vout)
{
    __shared__ short As[3][128][4][8]; // 3 x 8 KB
    __shared__ short Ws[3][128][4][8];
    const int tid = threadIdx.x, wave = tid >> 6, lane = tid & 63;
    const int lr = lane & 15, lc = lane >> 4;
    const int wm = (wave >> 1) * 64, wn = (wave & 1) * 64;
    const int m0 = blockIdx.x * 128;
    const int y = blockIdx.y;

    const unsigned short* W; const float* bias; int n0;
    if (y == 0)      { W = Wq; bias = bq; n0 = 0; }
    else if (y == 1) { W = Wk; bias = bk; n0 = 0; }
    else             { W = Wv; bias = bv; n0 = (y - 2) * 128; }

    floatx4 acc[4][4] = {};

    const int srow = lane >> 2, sch = lane & 3;
    const unsigned short* Ag0 = A + (long)(m0 + wave * 32 + srow) * CDIM + sch * 8;
    const unsigned short* Ag1 = Ag0 + (long)16 * CDIM;
    const unsigned short* Wg0 = W + (long)(n0 + wave * 32 + srow) * CDIM + sch * 8;
    const unsigned short* Wg1 = Wg0 + (long)16 * CDIM;

    short* ar = &As[0][0][0][0]; short* aw = &As[1][0][0][0]; short* a2 = &As[2][0][0][0];
    short* wr = &Ws[0][0][0][0]; short* ww = &Ws[1][0][0][0]; short* w2 = &Ws[2][0][0][0];

#define GSTAGE(K0, AD, WD) {                          \
        async16(Ag0 + (K0), (AD) + wave * 1024);      \
        async16(Ag1 + (K0), (AD) + wave * 1024 + 512);\
        async16(Wg0 + (K0), (WD) + wave * 1024);      \
        async16(Wg1 + (K0), (WD) + wave * 1024 + 512); }

    GSTAGE(0, ar, wr);
    for (int k0 = 0; k0 < CDIM; k0 += 32) {
        if (k0 + 32 < CDIM) {
            GSTAGE(k0 + 32, aw, ww);
            __builtin_amdgcn_sched_barrier(0);
            asm volatile("s_waitcnt vmcnt(4)" ::: "memory");
        } else {
            asm volatile("s_waitcnt vmcnt(0)" ::: "memory");
        }
        __builtin_amdgcn_sched_barrier(0);
        __builtin_amdgcn_s_barrier();
        __builtin_amdgcn_sched_barrier(0);
        short8 af[4], bfg[4];
#pragma unroll
        for (int i = 0; i < 4; i++) af[i]  = *(short8*)(ar + (wm + i * 16 + lr) * 32 + lc * 8);
#pragma unroll
        for (int j = 0; j < 4; j++) bfg[j] = *(short8*)(wr + (wn + j * 16 + lr) * 32 + lc * 8);
#pragma unroll
        for (int i = 0; i < 4; i++)
#pragma unroll
            for (int j = 0; j < 4; j++)
                acc[i][j] = __builtin_amdgcn_mfma_f32_16x16x32_bf16(af[i], bfg[j], acc[i][j], 0, 0, 0);
        short* t;
        t = ar; ar = aw; aw = a2; a2 = t;
        t = wr; wr = ww; ww = w2; w2 = t;
    }
#undef GSTAGE

#pragma unroll
    for (int i = 0; i < 4; i++) {
        int t0 = m0 + wm + i * 16 + lc * 4;
#pragma unroll
        for (int j = 0; j < 4; j++) {
            int c = n0 + wn + j * 16 + lr;  // absolute for v; ==local for q/k (n0=0)
            float bb = bias[c];
            if (y == 0) {
#pragma unroll
                for (int r = 0; r < 4; r++)
                    qout[(long)(t0 + r) * HDIM + c] = f2bf(acc[i][j][r] + bb);
            } else if (y == 1) {
#pragma unroll
                for (int r = 0; r < 4; r++) {
                    int tok = t0 + r;
                    kout[(tok >> 5) * 4096 + (c >> 3) * 256 + (tok & 31) * 8 + (c & 7)] =
                        f2bf(acc[i][j][r] + bb);
                }
            } else {
                ushort4 pk;
                pk.x = f2bf(acc[i][j][0] + bb); pk.y = f2bf(acc[i][j][1] + bb);
                pk.z = f2bf(acc[i][j][2] + bb); pk.w = f2bf(acc[i][j][3] + bb);
                long off = (long)(c >> 8) * 2097152 + (t0 >> 5) * 8192 +
                           ((t0 & 31) >> 3) * 2048 + (c & 255) * 8 + (t0 & 7);
                *(ushort4*)&vout[off] = pk;
            }
        }
    }
}

// ---------------- output projection: 128-tile NT GEMM, T3/T4 K-loop, f32 out ----------------
__global__ __launch_bounds__(256, 2) void gemm_out(
    const unsigned short* __restrict__ A, const unsigned short* __restrict__ W,
    const float* __restrict__ bias, float* __restrict__ out)
{
    __shared__ short As[3][128][4][8];
    __shared__ short Ws[3][128][4][8];
    const int tid = threadIdx.x, wave = tid >> 6, lane = tid & 63;
    const int lr = lane & 15, lc = lane >> 4;
    const int wm = (wave >> 1) * 64, wn = (wave & 1) * 64;
    const int m0 = blockIdx.x * 128, n0 = blockIdx.y * 128;

    floatx4 acc[4][4] = {};

    const int srow = lane >> 2, sch = lane & 3;
    const unsigned short* Ag0 = A + (long)(m0 + wave * 32 + srow) * CDIM + sch * 8;
    const unsigned short* Ag1 = Ag0 + (long)16 * CDIM;
    const unsigned short* Wg0 = W + (long)(n0 + wave * 32 + srow) * CDIM + sch * 8;
    const unsigned short* Wg1 = Wg0 + (long)16 * CDIM;

    short* ar = &As[0][0][0][0]; short* aw = &As[1][0][0][0]; short* a2 = &As[2][0][0][0];
    short* wr = &Ws[0][0][0][0]; short* ww = &Ws[1][0][0][0]; short* w2 = &Ws[2][0][0][0];

#define GSTAGE(K0, AD, WD) {                          \
        async16(Ag0 + (K0), (AD) + wave * 1024);      \
        async16(Ag1 + (K0), (AD) + wave * 1024 + 512);\
        async16(Wg0 + (K0), (WD) + wave * 1024);      \
        async16(Wg1 + (K0), (WD) + wave * 1024 + 512); }

    GSTAGE(0, ar, wr);
    for (int k0 = 0; k0 < CDIM; k0 += 32) {
        if (k0 + 32 < CDIM) {
            GSTAGE(k0 + 32, aw, ww);
            __builtin_amdgcn_sched_barrier(0);
            asm volatile("s_waitcnt vmcnt(4)" ::: "memory");
        } else {
            asm volatile("s_waitcnt vmcnt(0)" ::: "memory");
        }
        __builtin_amdgcn_sched_barrier(0);
        __builtin_amdgcn_s_barrier();
        __builtin_amdgcn_sched_barrier(0);
        short8 af[4], bfg[4];
#pragma unroll
        for (int i = 0; i < 4; i++) af[i]  = *(short8*)(ar + (wm + i * 16 + lr) * 32 + lc * 8);
#pragma unroll
        for (int j = 0; j < 4; j++) bfg[j] = *(short8*)(wr + (wn + j * 16 + lr) * 32 + lc * 8);
#pragma unroll
        for (int i = 0; i < 4; i++)
#pragma unroll
            for (int j = 0; j < 4; j++)
                acc[i][j] = __builtin_amdgcn_mfma_f32_16x16x32_bf16(af[i], bfg[j], acc[i][j], 0, 0, 0);
        short* t;
        t = ar; ar = aw; aw = a2; a2 = t;
        t = wr; wr = ww; ww = w2; w2 = t;
    }
#undef GSTAGE

#pragma unroll
    for (int i = 0; i < 4; i++) {
        int t0 = m0 + wm + i * 16 + lc * 4;
#pragma unroll
        for (int j = 0; j < 4; j++) {
            int c = n0 + wn + j * 16 + lr;
            float bb = bias[c];
#pragma unroll
            for (int r = 0; r < 4; r++) out[(long)(t0 + r) * CDIM + c] = acc[i][j][r] + bb;
        }
    }
}

// ---------------- fused attention: partial O = exp(QK^T*scale) @ V + rowsum ----------------
// Round-10 structure (8-wave block, 64 phases x 2 tiles, triple-buffered slots, counted
// vmcnt(6), in-reg P via cvt_pk+permlane32_swap). Unchanged.
__global__ __launch_bounds__(512, 2) void attn_pv(
    const unsigned short* __restrict__ qb, const unsigned short* __restrict__ ksw,
    const unsigned short* __restrict__ vsw,
    unsigned short* __restrict__ Oa, unsigned short* __restrict__ Ob,
    float* __restrict__ la, float* __restrict__ lb)
{
    __shared__ short Ks[3][8192];   // 48 KB
    __shared__ short Vs[3][16384];  // 96 KB

    const int tid = threadIdx.x, wave = tid >> 6, lane = tid & 63;
    const int l31 = lane & 31, h = lane >> 5;
    const int m0 = blockIdx.x * 256, cblk = blockIdx.y;
    const int mw = m0 + wave * 32;
    const int nt0 = blockIdx.z * 128;
    unsigned short* Op = blockIdx.z ? Ob : Oa;
    float* ls = blockIdx.z ? lb : la;
    const float cexp = (float)(0.08838834764831845 * 1.4426950408889634);

    short8 qf[8];
#pragma unroll
    for (int kk = 0; kk < 8; kk++)
        qf[kk] = *(const short8*)&qb[(mw + l31) * HDIM + kk * 16 + h * 8];

    floatx16 acc[8] = {};
    float ls0 = 0.f, ls1 = 0.f, ls2 = 0.f, ls3 = 0.f;

    const unsigned short* kg0 = ksw + (wave * 2 + 0) * 512 + lane * 8;
    const unsigned short* kg1 = ksw + (wave * 2 + 1) * 512 + lane * 8;
    const unsigned short* vgb = vsw + (long)cblk * 2097152 + lane * 8;
    const unsigned short* vg0 = vgb + (wave * 4 + 0) * 512;
    const unsigned short* vg1 = vgb + (wave * 4 + 1) * 512;
    const unsigned short* vg2 = vgb + (wave * 4 + 2) * 512;
    const unsigned short* vg3 = vgb + (wave * 4 + 3) * 512;

    short* kr = &Ks[0][0];
    short* kw = &Ks[1][0];
    short* k2 = &Ks[2][0];
    short* vr = &Vs[0][0];
    short* vw = &Vs[1][0];
    short* v2 = &Vs[2][0];

#define STAGE(P, KD, VD)                                                \
    {                                                                   \
        long ok_ = (long)(nt0 + 2 * (P)) * 4096;                        \
        long ov_ = (long)(nt0 + 2 * (P)) * 8192;                        \
        async16(kg0 + ok_, (KD) + (wave * 2 + 0) * 512);                \
        async16(kg1 + ok_, (KD) + (wave * 2 + 1) * 512);                \
        async16(vg0 + ov_, (VD) + (wave * 4 + 0) * 512);                \
        async16(vg1 + ov_, (VD) + (wave * 4 + 1) * 512);                \
        async16(vg2 + ov_, (VD) + (wave * 4 + 2) * 512);                \
        async16(vg3 + ov_, (VD) + (wave * 4 + 3) * 512);                \
    }

    STAGE(0, kr, vr);

    for (int ph = 0; ph < 64; ++ph) {
        if (ph + 1 < 64) STAGE(ph + 1, kw, vw);
        __builtin_amdgcn_sched_barrier(0);
        if (ph == 63) asm volatile("s_waitcnt vmcnt(0)" ::: "memory");
        else          asm volatile("s_waitcnt vmcnt(6)" ::: "memory");
        __builtin_amdgcn_sched_barrier(0);
        __builtin_amdgcn_s_barrier();
        __builtin_amdgcn_sched_barrier(0);

        short* kb0 = kr;        short* vb0 = vr;
        short* kb1 = kr + 4096; short* vb1 = vr + 8192;

        floatx16 st0 = {}, st1 = {};
        __builtin_amdgcn_s_setprio(1);
#pragma unroll
        for (int kk = 0; kk < 8; kk++) {
            short8 kf0 = *(short8*)(kb0 + (kk * 2 + h) * 256 + l31 * 8);
            short8 kf1 = *(short8*)(kb1 + (kk * 2 + h) * 256 + l31 * 8);
            st0 = __builtin_amdgcn_mfma_f32_32x32x16_bf16(kf0, qf[kk], st0, 0, 0, 0);
            st1 = __builtin_amdgcn_mfma_f32_32x32x16_bf16(kf1, qf[kk], st1, 0, 0, 0);
        }
        __builtin_amdgcn_s_setprio(0);

#define EXP_PACK(ST, PA0, PA1)                                                      \
        short8 PA0, PA1;                                                            \
        {                                                                           \
            unsigned pk0, pk1, pk2, pk3, pk4, pk5, pk6, pk7;                        \
            float p0, p1;                                                           \
            p0 = __builtin_amdgcn_exp2f(ST[0] * cexp);                              \
            p1 = __builtin_amdgcn_exp2f(ST[1] * cexp);                              \
            ls0 += p0 + p1;                                                         \
            asm("v_cvt_pk_bf16_f32 %0, %1, %2" : "=v"(pk0) : "v"(p0), "v"(p1));     \
            p0 = __builtin_amdgcn_exp2f(ST[2] * cexp);                              \
            p1 = __builtin_amdgcn_exp2f(ST[3] * cexp);                              \
            ls1 += p0 + p1;                                                         \
            asm("v_cvt_pk_bf16_f32 %0, %1, %2" : "=v"(pk1) : "v"(p0), "v"(p1));     \
            p0 = __builtin_amdgcn_exp2f(ST[4] * cexp);                              \
            p1 = __builtin_amdgcn_exp2f(ST[5] * cexp);                              \
            ls2 += p0 + p1;                                                         \
            asm("v_cvt_pk_bf16_f32 %0, %1, %2" : "=v"(pk2) : "v"(p0), "v"(p1));     \
            p0 = __builtin_amdgcn_exp2f(ST[6] * cexp);                              \
            p1 = __builtin_amdgcn_exp2f(ST[7] * cexp);                              \
            ls3 += p0 + p1;                                                         \
            asm("v_cvt_pk_bf16_f32 %0, %1, %2" : "=v"(pk3) : "v"(p0), "v"(p1));     \
            p0 = __builtin_amdgcn_exp2f(ST[8] * cexp);                              \
            p1 = __builtin_amdgcn_exp2f(ST[9] * cexp);                              \
            ls0 += p0 + p1;                                                         \
            asm("v_cvt_pk_bf16_f32 %0, %1, %2" : "=v"(pk4) : "v"(p0), "v"(p1));     \
            p0 = __builtin_amdgcn_exp2f(ST[10] * cexp);                             \
            p1 = __builtin_amdgcn_exp2f(ST[11] * cexp);                             \
            ls1 += p0 + p1;                                                         \
            asm("v_cvt_pk_bf16_f32 %0, %1, %2" : "=v"(pk5) : "v"(p0), "v"(p1));     \
            p0 = __builtin_amdgcn_exp2f(ST[12] * cexp);                             \
            p1 = __builtin_amdgcn_exp2f(ST[13] * cexp);                             \
            ls2 += p0 + p1;                                                         \
            asm("v_cvt_pk_bf16_f32 %0, %1, %2" : "=v"(pk6) : "v"(p0), "v"(p1));     \
            p0 = __builtin_amdgcn_exp2f(ST[14] * cexp);                             \
            p1 = __builtin_amdgcn_exp2f(ST[15] * cexp);                             \
            ls3 += p0 + p1;                                                         \
            asm("v_cvt_pk_bf16_f32 %0, %1, %2" : "=v"(pk7) : "v"(p0), "v"(p1));     \
            asm("v_permlane32_swap_b32 %0, %1" : "+v"(pk0), "+v"(pk2));             \
            asm("v_permlane32_swap_b32 %0, %1" : "+v"(pk1), "+v"(pk3));             \
            asm("v_permlane32_swap_b32 %0, %1" : "+v"(pk4), "+v"(pk6));             \
            asm("v_permlane32_swap_b32 %0, %1" : "+v"(pk5), "+v"(pk7));             \
            union { unsigned u[4]; short8 s; } up0_, up1_;                          \
            up0_.u[0] = pk0; up0_.u[1] = pk1; up0_.u[2] = pk2; up0_.u[3] = pk3;     \
            up1_.u[0] = pk4; up1_.u[1] = pk5; up1_.u[2] = pk6; up1_.u[3] = pk7;     \
            PA0 = up0_.s; PA1 = up1_.s;                                             \
        }

#define PV(VB, PA0, PA1)                                                            \
        __builtin_amdgcn_s_setprio(1);                                              \
        _Pragma("unroll")                                                           \
        for (int ct = 0; ct < 8; ct++) {                                            \
            short8 bv0 = *(short8*)((VB) + h * 2048 + (ct * 32 + l31) * 8);         \
            short8 bv1 = *(short8*)((VB) + (2 + h) * 2048 + (ct * 32 + l31) * 8);   \
            acc[ct] = __builtin_amdgcn_mfma_f32_32x32x16_bf16(PA0, bv0, acc[ct], 0, 0, 0); \
            acc[ct] = __builtin_amdgcn_mfma_f32_32x32x16_bf16(PA1, bv1, acc[ct], 0, 0, 0); \
        }                                                                           \
        __builtin_amdgcn_s_setprio(0);

        EXP_PACK(st0, pa0_0, pa1_0)
        EXP_PACK(st1, pa0_1, pa1_1)
        PV(vb0, pa0_0, pa1_0)
        PV(vb1, pa0_1, pa1_1)

#undef EXP_PACK
#undef PV

        short* t0p = kr; kr = kw; kw = k2; k2 = t0p;
        short* t1p = vr; vr = vw; vw = v2; v2 = t1p;
    }
#undef STAGE

#pragma unroll
    for (int ct = 0; ct < 8; ct++) {
        int c = cblk * 256 + ct * 32 + l31;
#pragma unroll
        for (int r = 0; r < 16; r++) {
            int q = (r & 3) + 8 * (r >> 2) + 4 * h;
            Op[(long)(mw + q) * CDIM + c] = f2bf(acc[ct][r]);
        }
    }
    if (blockIdx.y == 0) {
        float lsum = (ls0 + ls1) + (ls2 + ls3);
        lsum += __shfl_xor(lsum, 32);
        if (lane < 32) ls[mw + lane] = lsum;
    }
}

// ---------------- combine: attn = (Oa + Ob) / (la + lb), in place over Ob ----------------
__global__ __launch_bounds__(256) void combine_attn(
    const unsigned short* __restrict__ Oa, unsigned short* __restrict__ Ob,
    const float* __restrict__ la, const float* __restrict__ lb)
{
    int i = blockIdx.x * blockDim.x + threadIdx.x;
    int row = i >> 7;
    float inv = 1.0f / (la[row] + lb[row]);
    short8 a = ((const short8*)Oa)[i];
    short8 b = ((const short8*)Ob)[i];
    short8 o;
#pragma unroll
    for (int e = 0; e < 8; e++) o[e] = (short)f2bf((bf2f(a[e]) + bf2f(b[e])) * inv);
    ((short8*)Ob)[i] = o;
}

extern "C" void kernel_launch(void* const* d_in, const int* in_sizes, int n_in,
                              void* d_out, int out_size, void* d_ws, size_t ws_size,
                              hipStream_t stream) {
    const float* x  = (const float*)d_in[0];
    const float* Wq = (const float*)d_in[1];
    const float* bq = (const float*)d_in[2];
    const float* Wk = (const float*)d_in[3];
    const float* bk = (const float*)d_in[4];
    const float* Wv = (const float*)d_in[5];
    const float* bv = (const float*)d_in[6];
    const float* Wo = (const float*)d_in[7];
    const float* bo = (const float*)d_in[8];

    char* ws = (char*)d_ws;
    unsigned short* x_bf   = (unsigned short*)(ws + 0);          // 16 MB (reused as Oa)
    unsigned short* wq_bf  = (unsigned short*)(ws + 16777216);   // 256 KB
    unsigned short* wk_bf  = (unsigned short*)(ws + 17039360);   // 256 KB
    unsigned short* wv_bf  = (unsigned short*)(ws + 17301504);   // 2 MB
    unsigned short* wo_bf  = (unsigned short*)(ws + 19398656);   // 2 MB
    unsigned short* q_bf   = (unsigned short*)(ws + 21495808);   // 2 MB
    unsigned short* k_swz  = (unsigned short*)(ws + 23592960);   // 2 MB (K swizzled)
    unsigned short* v_swz  = (unsigned short*)(ws + 25690112);   // 16 MB (V swizzled)
    unsigned short* attn_bf= (unsigned short*)(ws + 42467328);   // 16 MB (Ob, combined in place)
    float* lsum_a          = (float*)(ws + 59244544);            // 32 KB
    float* lsum_b          = (float*)(ws + 59277312);            // 32 KB

    // all casts in one launch
    cast_all<<<10496, 256, 0, stream>>>(x, Wv, Wo, Wq, Wk,
                                        x_bf, wv_bf, wo_bf, wq_bf, wk_bf);

    // q/k/v projections in one launch (T3/T4 K-loop)
    gemm_proj<<<dim3(64, 10), 256, 0, stream>>>(x_bf, wq_bf, bq, wk_bf, bk, wv_bf, bv,
                                                q_bf, k_swz, v_swz);

    // fused attention (split-n over gridDim.z); Oa overlays dead x_bf
    attn_pv<<<dim3(32, 4, 2), 512, 0, stream>>>(q_bf, k_swz, v_swz,
                                                x_bf, attn_bf, lsum_a, lsum_b);
    combine_attn<<<4096, 256, 0, stream>>>(x_bf, attn_bf, lsum_a, lsum_b);

    // output projection (T3/T4 K-loop, f32 out)
    gemm_out<<<dim3(64, 8), 256, 0, stream>>>(attn_bf, wo_bf, bo, (float*)d_out);
}

// Round 12
// 336.179 us; speedup vs baseline: 1.5309x; 1.0225x over previous
//
#include <hip/hip_runtime.h>

#define NTOK 8192
#define CDIM 1024
#define HDIM 128

typedef __attribute__((ext_vector_type(8))) short short8;
typedef __attribute__((ext_vector_type(4))) float floatx4;
typedef __attribute__((ext_vector_type(16))) float floatx16;

__device__ inline unsigned short f2bf(float f) {
    union { float f; unsigned u; } v; v.f = f;
    unsigned r = v.u + 0x7fffu + ((v.u >> 16) & 1u);
    return (unsigned short)(r >> 16);
}
__device__ inline float bf2f(short s) {
    union { unsigned u; float f; } v;
    v.u = ((unsigned)(unsigned short)s) << 16;
    return v.f;
}
__device__ inline void async16(const unsigned short* g, short* l) {
    __builtin_amdgcn_global_load_lds(
        (const __attribute__((address_space(1))) unsigned*)g,
        (__attribute__((address_space(3))) unsigned*)l, 16, 0, 0);
}

// ---------------- fused cast fp32 -> bf16 for all 5 inputs (one launch) ----------------
__global__ __launch_bounds__(256) void cast_all(
    const float* __restrict__ x,  const float* __restrict__ Wv,
    const float* __restrict__ Wo, const float* __restrict__ Wq,
    const float* __restrict__ Wk,
    unsigned short* __restrict__ xo, unsigned short* __restrict__ wvo,
    unsigned short* __restrict__ woo, unsigned short* __restrict__ wqo,
    unsigned short* __restrict__ wko)
{
    int b = blockIdx.x;
    const float* in; unsigned short* out; int base;
    if (b < 8192)       { in = x;  out = xo;  base = b; }
    else if (b < 9216)  { in = Wv; out = wvo; base = b - 8192; }
    else if (b < 10240) { in = Wo; out = woo; base = b - 9216; }
    else if (b < 10368) { in = Wq; out = wqo; base = b - 10240; }
    else                { in = Wk; out = wko; base = b - 10368; }
    int i = base * 256 + threadIdx.x;
    float4 v = ((const float4*)in)[i];
    ushort4 o;
    o.x = f2bf(v.x); o.y = f2bf(v.y); o.z = f2bf(v.z); o.w = f2bf(v.w);
    ((ushort4*)out)[i] = o;
}

// ---------------- unified q/k/v projection: 128-tile NT GEMM, T3/T4 K-loop ----------------
// grid (64, 10): y=0 -> q (row-major bf16), y=1 -> k (K-swz), y>=2 -> v (V-swz, n0=(y-2)*128)
// ROUND 12: __launch_bounds__(256,3): LDS 48KB -> 3 blocks/CU = 768 resident slots, so the
// 640-block grid runs in ONE fill (was 512+128 tail wave at 25% utilization). Reg cap 170:
// acc 64 AGPR + ~75 VGPR fits (unified file).
__global__ __launch_bounds__(256, 3) void gemm_proj(
    const unsigned short* __restrict__ A,
    const unsigned short* __restrict__ Wq, const float* __restrict__ bq,
    const unsigned short* __restrict__ Wk, const float* __restrict__ bk,
    const unsigned short* __restrict__ Wv, const float* __restrict__ bv,
    unsigned short* __restrict__ qout, unsigned short* __restrict__ kout,
    unsigned short* __restrict__ vout)
{
    __shared__ short As[3][128][4][8]; // 3 x 8 KB
    __shared__ short Ws[3][128][4][8];
    const int tid = threadIdx.x, wave = tid >> 6, lane = tid & 63;
    const int lr = lane & 15, lc = lane >> 4;
    const int wm = (wave >> 1) * 64, wn = (wave & 1) * 64;
    const int m0 = blockIdx.x * 128;
    const int y = blockIdx.y;

    const unsigned short* W; const float* bias; int n0;
    if (y == 0)      { W = Wq; bias = bq; n0 = 0; }
    else if (y == 1) { W = Wk; bias = bk; n0 = 0; }
    else             { W = Wv; bias = bv; n0 = (y - 2) * 128; }

    floatx4 acc[4][4] = {};

    const int srow = lane >> 2, sch = lane & 3;
    const unsigned short* Ag0 = A + (long)(m0 + wave * 32 + srow) * CDIM + sch * 8;
    const unsigned short* Ag1 = Ag0 + (long)16 * CDIM;
    const unsigned short* Wg0 = W + (long)(n0 + wave * 32 + srow) * CDIM + sch * 8;
    const unsigned short* Wg1 = Wg0 + (long)16 * CDIM;

    short* ar = &As[0][0][0][0]; short* aw = &As[1][0][0][0]; short* a2 = &As[2][0][0][0];
    short* wr = &Ws[0][0][0][0]; short* ww = &Ws[1][0][0][0]; short* w2 = &Ws[2][0][0][0];

#define GSTAGE(K0, AD, WD) {                          \
        async16(Ag0 + (K0), (AD) + wave * 1024);      \
        async16(Ag1 + (K0), (AD) + wave * 1024 + 512);\
        async16(Wg0 + (K0), (WD) + wave * 1024);      \
        async16(Wg1 + (K0), (WD) + wave * 1024 + 512); }

    GSTAGE(0, ar, wr);
    for (int k0 = 0; k0 < CDIM; k0 += 32) {
        if (k0 + 32 < CDIM) {
            GSTAGE(k0 + 32, aw, ww);
            __builtin_amdgcn_sched_barrier(0);
            asm volatile("s_waitcnt vmcnt(4)" ::: "memory");
        } else {
            asm volatile("s_waitcnt vmcnt(0)" ::: "memory");
        }
        __builtin_amdgcn_sched_barrier(0);
        __builtin_amdgcn_s_barrier();
        __builtin_amdgcn_sched_barrier(0);
        short8 af[4], bfg[4];
#pragma unroll
        for (int i = 0; i < 4; i++) af[i]  = *(short8*)(ar + (wm + i * 16 + lr) * 32 + lc * 8);
#pragma unroll
        for (int j = 0; j < 4; j++) bfg[j] = *(short8*)(wr + (wn + j * 16 + lr) * 32 + lc * 8);
#pragma unroll
        for (int i = 0; i < 4; i++)
#pragma unroll
            for (int j = 0; j < 4; j++)
                acc[i][j] = __builtin_amdgcn_mfma_f32_16x16x32_bf16(af[i], bfg[j], acc[i][j], 0, 0, 0);
        short* t;
        t = ar; ar = aw; aw = a2; a2 = t;
        t = wr; wr = ww; ww = w2; w2 = t;
    }
#undef GSTAGE

#pragma unroll
    for (int i = 0; i < 4; i++) {
        int t0 = m0 + wm + i * 16 + lc * 4;
#pragma unroll
        for (int j = 0; j < 4; j++) {
            int c = n0 + wn + j * 16 + lr;  // absolute for v; ==local for q/k (n0=0)
            float bb = bias[c];
            if (y == 0) {
#pragma unroll
                for (int r = 0; r < 4; r++)
                    qout[(long)(t0 + r) * HDIM + c] = f2bf(acc[i][j][r] + bb);
            } else if (y == 1) {
#pragma unroll
                for (int r = 0; r < 4; r++) {
                    int tok = t0 + r;
                    kout[(tok >> 5) * 4096 + (c >> 3) * 256 + (tok & 31) * 8 + (c & 7)] =
                        f2bf(acc[i][j][r] + bb);
                }
            } else {
                ushort4 pk;
                pk.x = f2bf(acc[i][j][0] + bb); pk.y = f2bf(acc[i][j][1] + bb);
                pk.z = f2bf(acc[i][j][2] + bb); pk.w = f2bf(acc[i][j][3] + bb);
                long off = (long)(c >> 8) * 2097152 + (t0 >> 5) * 8192 +
                           ((t0 & 31) >> 3) * 2048 + (c & 255) * 8 + (t0 & 7);
                *(ushort4*)&vout[off] = pk;
            }
        }
    }
}

// ---------------- output projection: 128-tile NT GEMM, T3/T4 K-loop, f32 out ----------------
// ROUND 12: 3 blocks/CU (512 blocks on 768 slots -> deeper co-residency / latency hiding).
__global__ __launch_bounds__(256, 3) void gemm_out(
    const unsigned short* __restrict__ A, const unsigned short* __restrict__ W,
    const float* __restrict__ bias, float* __restrict__ out)
{
    __shared__ short As[3][128][4][8];
    __shared__ short Ws[3][128][4][8];
    const int tid = threadIdx.x, wave = tid >> 6, lane = tid & 63;
    const int lr = lane & 15, lc = lane >> 4;
    const int wm = (wave >> 1) * 64, wn = (wave & 1) * 64;
    const int m0 = blockIdx.x * 128, n0 = blockIdx.y * 128;

    floatx4 acc[4][4] = {};

    const int srow = lane >> 2, sch = lane & 3;
    const unsigned short* Ag0 = A + (long)(m0 + wave * 32 + srow) * CDIM + sch * 8;
    const unsigned short* Ag1 = Ag0 + (long)16 * CDIM;
    const unsigned short* Wg0 = W + (long)(n0 + wave * 32 + srow) * CDIM + sch * 8;
    const unsigned short* Wg1 = Wg0 + (long)16 * CDIM;

    short* ar = &As[0][0][0][0]; short* aw = &As[1][0][0][0]; short* a2 = &As[2][0][0][0];
    short* wr = &Ws[0][0][0][0]; short* ww = &Ws[1][0][0][0]; short* w2 = &Ws[2][0][0][0];

#define GSTAGE(K0, AD, WD) {                          \
        async16(Ag0 + (K0), (AD) + wave * 1024);      \
        async16(Ag1 + (K0), (AD) + wave * 1024 + 512);\
        async16(Wg0 + (K0), (WD) + wave * 1024);      \
        async16(Wg1 + (K0), (WD) + wave * 1024 + 512); }

    GSTAGE(0, ar, wr);
    for (int k0 = 0; k0 < CDIM; k0 += 32) {
        if (k0 + 32 < CDIM) {
            GSTAGE(k0 + 32, aw, ww);
            __builtin_amdgcn_sched_barrier(0);
            asm volatile("s_waitcnt vmcnt(4)" ::: "memory");
        } else {
            asm volatile("s_waitcnt vmcnt(0)" ::: "memory");
        }
        __builtin_amdgcn_sched_barrier(0);
        __builtin_amdgcn_s_barrier();
        __builtin_amdgcn_sched_barrier(0);
        short8 af[4], bfg[4];
#pragma unroll
        for (int i = 0; i < 4; i++) af[i]  = *(short8*)(ar + (wm + i * 16 + lr) * 32 + lc * 8);
#pragma unroll
        for (int j = 0; j < 4; j++) bfg[j] = *(short8*)(wr + (wn + j * 16 + lr) * 32 + lc * 8);
#pragma unroll
        for (int i = 0; i < 4; i++)
#pragma unroll
            for (int j = 0; j < 4; j++)
                acc[i][j] = __builtin_amdgcn_mfma_f32_16x16x32_bf16(af[i], bfg[j], acc[i][j], 0, 0, 0);
        short* t;
        t = ar; ar = aw; aw = a2; a2 = t;
        t = wr; wr = ww; ww = w2; w2 = t;
    }
#undef GSTAGE

#pragma unroll
    for (int i = 0; i < 4; i++) {
        int t0 = m0 + wm + i * 16 + lc * 4;
#pragma unroll
        for (int j = 0; j < 4; j++) {
            int c = n0 + wn + j * 16 + lr;
            float bb = bias[c];
#pragma unroll
            for (int r = 0; r < 4; r++) out[(long)(t0 + r) * CDIM + c] = acc[i][j][r] + bb;
        }
    }
}

// ---------------- fused attention: partial O = exp(QK^T*scale) @ V + rowsum ----------------
// Round-10 structure (8-wave block, 64 phases x 2 tiles, triple-buffered slots, counted
// vmcnt(6), in-reg P via cvt_pk+permlane32_swap). Unchanged — at its structural floor:
// unified reg file (116 VGPR + 128 AGPR ~ 244/wave) caps occupancy at 2 waves/SIMD.
__global__ __launch_bounds__(512, 2) void attn_pv(
    const unsigned short* __restrict__ qb, const unsigned short* __restrict__ ksw,
    const unsigned short* __restrict__ vsw,
    unsigned short* __restrict__ Oa, unsigned short* __restrict__ Ob,
    float* __restrict__ la, float* __restrict__ lb)
{
    __shared__ short Ks[3][8192];   // 48 KB
    __shared__ short Vs[3][16384];  // 96 KB

    const int tid = threadIdx.x, wave = tid >> 6, lane = tid & 63;
    const int l31 = lane & 31, h = lane >> 5;
    const int m0 = blockIdx.x * 256, cblk = blockIdx.y;
    const int mw = m0 + wave * 32;
    const int nt0 = blockIdx.z * 128;
    unsigned short* Op = blockIdx.z ? Ob : Oa;
    float* ls = blockIdx.z ? lb : la;
    const float cexp = (float)(0.08838834764831845 * 1.4426950408889634);

    short8 qf[8];
#pragma unroll
    for (int kk = 0; kk < 8; kk++)
        qf[kk] = *(const short8*)&qb[(mw + l31) * HDIM + kk * 16 + h * 8];

    floatx16 acc[8] = {};
    float ls0 = 0.f, ls1 = 0.f, ls2 = 0.f, ls3 = 0.f;

    const unsigned short* kg0 = ksw + (wave * 2 + 0) * 512 + lane * 8;
    const unsigned short* kg1 = ksw + (wave * 2 + 1) * 512 + lane * 8;
    const unsigned short* vgb = vsw + (long)cblk * 2097152 + lane * 8;
    const unsigned short* vg0 = vgb + (wave * 4 + 0) * 512;
    const unsigned short* vg1 = vgb + (wave * 4 + 1) * 512;
    const unsigned short* vg2 = vgb + (wave * 4 + 2) * 512;
    const unsigned short* vg3 = vgb + (wave * 4 + 3) * 512;

    short* kr = &Ks[0][0];
    short* kw = &Ks[1][0];
    short* k2 = &Ks[2][0];
    short* vr = &Vs[0][0];
    short* vw = &Vs[1][0];
    short* v2 = &Vs[2][0];

#define STAGE(P, KD, VD)                                                \
    {                                                                   \
        long ok_ = (long)(nt0 + 2 * (P)) * 4096;                        \
        long ov_ = (long)(nt0 + 2 * (P)) * 8192;                        \
        async16(kg0 + ok_, (KD) + (wave * 2 + 0) * 512);                \
        async16(kg1 + ok_, (KD) + (wave * 2 + 1) * 512);                \
        async16(vg0 + ov_, (VD) + (wave * 4 + 0) * 512);                \
        async16(vg1 + ov_, (VD) + (wave * 4 + 1) * 512);                \
        async16(vg2 + ov_, (VD) + (wave * 4 + 2) * 512);                \
        async16(vg3 + ov_, (VD) + (wave * 4 + 3) * 512);                \
    }

    STAGE(0, kr, vr);

    for (int ph = 0; ph < 64; ++ph) {
        if (ph + 1 < 64) STAGE(ph + 1, kw, vw);
        __builtin_amdgcn_sched_barrier(0);
        if (ph == 63) asm volatile("s_waitcnt vmcnt(0)" ::: "memory");
        else          asm volatile("s_waitcnt vmcnt(6)" ::: "memory");
        __builtin_amdgcn_sched_barrier(0);
        __builtin_amdgcn_s_barrier();
        __builtin_amdgcn_sched_barrier(0);

        short* kb0 = kr;        short* vb0 = vr;
        short* kb1 = kr + 4096; short* vb1 = vr + 8192;

        floatx16 st0 = {}, st1 = {};
        __builtin_amdgcn_s_setprio(1);
#pragma unroll
        for (int kk = 0; kk < 8; kk++) {
            short8 kf0 = *(short8*)(kb0 + (kk * 2 + h) * 256 + l31 * 8);
            short8 kf1 = *(short8*)(kb1 + (kk * 2 + h) * 256 + l31 * 8);
            st0 = __builtin_amdgcn_mfma_f32_32x32x16_bf16(kf0, qf[kk], st0, 0, 0, 0);
            st1 = __builtin_amdgcn_mfma_f32_32x32x16_bf16(kf1, qf[kk], st1, 0, 0, 0);
        }
        __builtin_amdgcn_s_setprio(0);

#define EXP_PACK(ST, PA0, PA1)                                                      \
        short8 PA0, PA1;                                                            \
        {                                                                           \
            unsigned pk0, pk1, pk2, pk3, pk4, pk5, pk6, pk7;                        \
            float p0, p1;                                                           \
            p0 = __builtin_amdgcn_exp2f(ST[0] * cexp);                              \
            p1 = __builtin_amdgcn_exp2f(ST[1] * cexp);                              \
            ls0 += p0 + p1;                                                         \
            asm("v_cvt_pk_bf16_f32 %0, %1, %2" : "=v"(pk0) : "v"(p0), "v"(p1));     \
            p0 = __builtin_amdgcn_exp2f(ST[2] * cexp);                              \
            p1 = __builtin_amdgcn_exp2f(ST[3] * cexp);                              \
            ls1 += p0 + p1;                                                         \
            asm("v_cvt_pk_bf16_f32 %0, %1, %2" : "=v"(pk1) : "v"(p0), "v"(p1));     \
            p0 = __builtin_amdgcn_exp2f(ST[4] * cexp);                              \
            p1 = __builtin_amdgcn_exp2f(ST[5] * cexp);                              \
            ls2 += p0 + p1;                                                         \
            asm("v_cvt_pk_bf16_f32 %0, %1, %2" : "=v"(pk2) : "v"(p0), "v"(p1));     \
            p0 = __builtin_amdgcn_exp2f(ST[6] * cexp);                              \
            p1 = __builtin_amdgcn_exp2f(ST[7] * cexp);                              \
            ls3 += p0 + p1;                                                         \
            asm("v_cvt_pk_bf16_f32 %0, %1, %2" : "=v"(pk3) : "v"(p0), "v"(p1));     \
            p0 = __builtin_amdgcn_exp2f(ST[8] * cexp);                              \
            p1 = __builtin_amdgcn_exp2f(ST[9] * cexp);                              \
            ls0 += p0 + p1;                                                         \
            asm("v_cvt_pk_bf16_f32 %0, %1, %2" : "=v"(pk4) : "v"(p0), "v"(p1));     \
            p0 = __builtin_amdgcn_exp2f(ST[10] * cexp);                             \
            p1 = __builtin_amdgcn_exp2f(ST[11] * cexp);                             \
            ls1 += p0 + p1;                                                         \
            asm("v_cvt_pk_bf16_f32 %0, %1, %2" : "=v"(pk5) : "v"(p0), "v"(p1));     \
            p0 = __builtin_amdgcn_exp2f(ST[12] * cexp);                             \
            p1 = __builtin_amdgcn_exp2f(ST[13] * cexp);                             \
            ls2 += p0 + p1;                                                         \
            asm("v_cvt_pk_bf16_f32 %0, %1, %2" : "=v"(pk6) : "v"(p0), "v"(p1));     \
            p0 = __builtin_amdgcn_exp2f(ST[14] * cexp);                             \
            p1 = __builtin_amdgcn_exp2f(ST[15] * cexp);                             \
            ls3 += p0 + p1;                                                         \
            asm("v_cvt_pk_bf16_f32 %0, %1, %2" : "=v"(pk7) : "v"(p0), "v"(p1));     \
            asm("v_permlane32_swap_b32 %0, %1" : "+v"(pk0), "+v"(pk2));             \
            asm("v_permlane32_swap_b32 %0, %1" : "+v"(pk1), "+v"(pk3));             \
            asm("v_permlane32_swap_b32 %0, %1" : "+v"(pk4), "+v"(pk6));             \
            asm("v_permlane32_swap_b32 %0, %1" : "+v"(pk5), "+v"(pk7));             \
            union { unsigned u[4]; short8 s; } up0_, up1_;                          \
            up0_.u[0] = pk0; up0_.u[1] = pk1; up0_.u[2] = pk2; up0_.u[3] = pk3;     \
            up1_.u[0] = pk4; up1_.u[1] = pk5; up1_.u[2] = pk6; up1_.u[3] = pk7;     \
            PA0 = up0_.s; PA1 = up1_.s;                                             \
        }

#define PV(VB, PA0, PA1)                                                            \
        __builtin_amdgcn_s_setprio(1);                                              \
        _Pragma("unroll")                                                           \
        for (int ct = 0; ct < 8; ct++) {                                            \
            short8 bv0 = *(short8*)((VB) + h * 2048 + (ct * 32 + l31) * 8);         \
            short8 bv1 = *(short8*)((VB) + (2 + h) * 2048 + (ct * 32 + l31) * 8);   \
            acc[ct] = __builtin_amdgcn_mfma_f32_32x32x16_bf16(PA0, bv0, acc[ct], 0, 0, 0); \
            acc[ct] = __builtin_amdgcn_mfma_f32_32x32x16_bf16(PA1, bv1, acc[ct], 0, 0, 0); \
        }                                                                           \
        __builtin_amdgcn_s_setprio(0);

        EXP_PACK(st0, pa0_0, pa1_0)
        EXP_PACK(st1, pa0_1, pa1_1)
        PV(vb0, pa0_0, pa1_0)
        PV(vb1, pa0_1, pa1_1)

#undef EXP_PACK
#undef PV

        short* t0p = kr; kr = kw; kw = k2; k2 = t0p;
        short* t1p = vr; vr = vw; vw = v2; v2 = t1p;
    }
#undef STAGE

#pragma unroll
    for (int ct = 0; ct < 8; ct++) {
        int c = cblk * 256 + ct * 32 + l31;
#pragma unroll
        for (int r = 0; r < 16; r++) {
            int q = (r & 3) + 8 * (r >> 2) + 4 * h;
            Op[(long)(mw + q) * CDIM + c] = f2bf(acc[ct][r]);
        }
    }
    if (blockIdx.y == 0) {
        float lsum = (ls0 + ls1) + (ls2 + ls3);
        lsum += __shfl_xor(lsum, 32);
        if (lane < 32) ls[mw + lane] = lsum;
    }
}

// ---------------- combine: attn = (Oa + Ob) / (la + lb), in place over Ob ----------------
__global__ __launch_bounds__(256) void combine_attn(
    const unsigned short* __restrict__ Oa, unsigned short* __restrict__ Ob,
    const float* __restrict__ la, const float* __restrict__ lb)
{
    int i = blockIdx.x * blockDim.x + threadIdx.x;
    int row = i >> 7;
    float inv = 1.0f / (la[row] + lb[row]);
    short8 a = ((const short8*)Oa)[i];
    short8 b = ((const short8*)Ob)[i];
    short8 o;
#pragma unroll
    for (int e = 0; e < 8; e++) o[e] = (short)f2bf((bf2f(a[e]) + bf2f(b[e])) * inv);
    ((short8*)Ob)[i] = o;
}

extern "C" void kernel_launch(void* const* d_in, const int* in_sizes, int n_in,
                              void* d_out, int out_size, void* d_ws, size_t ws_size,
                              hipStream_t stream) {
    const float* x  = (const float*)d_in[0];
    const float* Wq = (const float*)d_in[1];
    const float* bq = (const float*)d_in[2];
    const float* Wk = (const float*)d_in[3];
    const float* bk = (const float*)d_in[4];
    const float* Wv = (const float*)d_in[5];
    const float* bv = (const float*)d_in[6];
    const float* Wo = (const float*)d_in[7];
    const float* bo = (const float*)d_in[8];

    char* ws = (char*)d_ws;
    unsigned short* x_bf   = (unsigned short*)(ws + 0);          // 16 MB (reused as Oa)
    unsigned short* wq_bf  = (unsigned short*)(ws + 16777216);   // 256 KB
    unsigned short* wk_bf  = (unsigned short*)(ws + 17039360);   // 256 KB
    unsigned short* wv_bf  = (unsigned short*)(ws + 17301504);   // 2 MB
    unsigned short* wo_bf  = (unsigned short*)(ws + 19398656);   // 2 MB
    unsigned short* q_bf   = (unsigned short*)(ws + 21495808);   // 2 MB
    unsigned short* k_swz  = (unsigned short*)(ws + 23592960);   // 2 MB (K swizzled)
    unsigned short* v_swz  = (unsigned short*)(ws + 25690112);   // 16 MB (V swizzled)
    unsigned short* attn_bf= (unsigned short*)(ws + 42467328);   // 16 MB (Ob, combined in place)
    float* lsum_a          = (float*)(ws + 59244544);            // 32 KB
    float* lsum_b          = (float*)(ws + 59277312);            // 32 KB

    // all casts in one launch
    cast_all<<<10496, 256, 0, stream>>>(x, Wv, Wo, Wq, Wk,
                                        x_bf, wv_bf, wo_bf, wq_bf, wk_bf);

    // q/k/v projections in one launch (T3/T4 K-loop, 3 blocks/CU)
    gemm_proj<<<dim3(64, 10), 256, 0, stream>>>(x_bf, wq_bf, bq, wk_bf, bk, wv_bf, bv,
                                                q_bf, k_swz, v_swz);

    // fused attention (split-n over gridDim.z); Oa overlays dead x_bf
    attn_pv<<<dim3(32, 4, 2), 512, 0, stream>>>(q_bf, k_swz, v_swz,
                                                x_bf, attn_bf, lsum_a, lsum_b);
    combine_attn<<<4096, 256, 0, stream>>>(x_bf, attn_bf, lsum_a, lsum_b);

    // output projection (T3/T4 K-loop, 3 blocks/CU, f32 out)
    gemm_out<<<dim3(64, 8), 256, 0, stream>>>(attn_bf, wo_bf, bo, (float*)d_out);
}